// Round 12
// baseline (688.062 us; speedup 1.0000x reference)
//
#include <hip/hip_runtime.h>
#include <math.h>

#define N_NODES 100000
#define N_EDGES 1250000
#define NGRAPH 256
#define IN_DIM 8
#define DIM 64
#define BN_EPS 1e-5f

#define BSHIFT 11
#define BNODES 2048
#define NBUCK 49            // ceil(100000 / 2048)
#define NBLK_B 512
#define CHUNK 2442          // ceil(1250000 / 512)
#define POOL_ROWS 128

typedef unsigned short bf16_t;

static __device__ inline float bf2f(bf16_t u) {
    return __uint_as_float(((unsigned int)u) << 16);
}
static __device__ inline bf16_t f2bf(float f) {
    unsigned int b = __float_as_uint(f);
    b += 0x7fffu + ((b >> 16) & 1u);
    return (bf16_t)(b >> 16);
}

// ---------------- coarse bucket histogram (49 buckets, LDS-binned) ----------------

__global__ void __launch_bounds__(256) k_bhist(const int* __restrict__ dst,
                                               int* __restrict__ bucket_count) {
    __shared__ int lh[NBUCK];
    int tid = threadIdx.x;
    if (tid < NBUCK) lh[tid] = 0;
    __syncthreads();
    int e0 = blockIdx.x * CHUNK;
    int e1 = e0 + CHUNK; if (e1 > N_EDGES) e1 = N_EDGES;
    for (int e = e0 + tid; e < e1; e += 256)
        atomicAdd(&lh[dst[e] >> BSHIFT], 1);
    __syncthreads();
    if (tid < NBUCK) atomicAdd(&bucket_count[tid], lh[tid]);
}

// ---------------- bucket base scan (49 entries, trivial) ----------------

__global__ void k_bscan(const int* __restrict__ bucket_count, int* __restrict__ bucket_base,
                        int* __restrict__ bucket_cursor, int* __restrict__ offsets) {
    if (threadIdx.x == 0) {
        int acc = 0;
        for (int b = 0; b < NBUCK; ++b) {
            bucket_base[b] = acc;
            bucket_cursor[b] = acc;
            acc += bucket_count[b];
        }
        offsets[N_NODES] = N_EDGES;
    }
}

// ------- bucket fill: per-block LDS count -> contiguous chunk reservation -> burst writes -------

__global__ void __launch_bounds__(256) k_bfill(const int* __restrict__ src,
                                               const int* __restrict__ dst,
                                               const float2* __restrict__ edge_attr,
                                               int* __restrict__ bucket_cursor,
                                               int2* __restrict__ ebuf) {
    __shared__ int lh[NBUCK], lbase[NBUCK];
    int tid = threadIdx.x;
    if (tid < NBUCK) lh[tid] = 0;
    __syncthreads();
    int e0 = blockIdx.x * CHUNK;
    int e1 = e0 + CHUNK; if (e1 > N_EDGES) e1 = N_EDGES;
    for (int e = e0 + tid; e < e1; e += 256)
        atomicAdd(&lh[dst[e] >> BSHIFT], 1);
    __syncthreads();
    if (tid < NBUCK) {
        lbase[tid] = atomicAdd(&bucket_cursor[tid], lh[tid]);
        lh[tid] = 0;
    }
    __syncthreads();
    for (int e = e0 + tid; e < e1; e += 256) {
        int d = dst[e];
        int b = d >> BSHIFT;
        int pos = lbase[b] + atomicAdd(&lh[b], 1);
        int pk = src[e] | ((d & (BNODES - 1)) << 17);  // src<2^17, dlocal<2^11
        ebuf[pos] = make_int2(pk, __float_as_int(edge_attr[e].y));
    }
}

// ------- bucket sort: exact CSR placement + offsets + dinv/selfnorm, all LDS-local -------

__global__ void __launch_bounds__(512) k_bsort(
        const int* __restrict__ bucket_base, const int2* __restrict__ ebuf,
        int* __restrict__ offsets, int2* __restrict__ csr,
        float* __restrict__ dinv, float* __restrict__ selfnorm) {
    __shared__ int cnt[BNODES];
    __shared__ float wsum[BNODES];
    __shared__ int loff[BNODES];
    __shared__ int tsum[512];
    int tid = threadIdx.x;
    int b = blockIdx.x;
    int nbase = b * BNODES;
    int nend = nbase + BNODES; if (nend > N_NODES) nend = N_NODES;
    int nloc = nend - nbase;
    for (int i = tid; i < BNODES; i += 512) { cnt[i] = 0; wsum[i] = 0.0f; }
    __syncthreads();
    int e0 = bucket_base[b];
    int e1 = (b + 1 < NBUCK) ? bucket_base[b + 1] : N_EDGES;
    for (int e = e0 + tid; e < e1; e += 512) {
        int2 p = ebuf[e];
        int dl = p.x >> 17;
        atomicAdd(&cnt[dl], 1);
        atomicAdd(&wsum[dl], __int_as_float(p.y));
    }
    __syncthreads();
    int b4 = tid * 4;
    int c0 = cnt[b4], c1 = cnt[b4 + 1], c2 = cnt[b4 + 2], c3 = cnt[b4 + 3];
    tsum[tid] = c0 + c1 + c2 + c3;
    __syncthreads();
    for (int off = 1; off < 512; off <<= 1) {
        int add = (tid >= off) ? tsum[tid - off] : 0;
        __syncthreads();
        tsum[tid] += add;
        __syncthreads();
    }
    int excl = tsum[tid] - (c0 + c1 + c2 + c3);
    loff[b4] = excl;
    loff[b4 + 1] = excl + c0;
    loff[b4 + 2] = excl + c0 + c1;
    loff[b4 + 3] = excl + c0 + c1 + c2;
    __syncthreads();
    for (int i = tid; i < nloc; i += 512) {
        offsets[nbase + i] = e0 + loff[i];
        float r = rsqrtf(wsum[i] + 1.0f);  // +1 = self-loop weight
        dinv[nbase + i] = r;
        selfnorm[nbase + i] = r * r;
    }
    for (int i = tid; i < BNODES; i += 512) cnt[i] = loff[i];  // cursor
    __syncthreads();
    for (int e = e0 + tid; e < e1; e += 512) {
        int2 p = ebuf[e];
        int dl = p.x >> 17;
        int pos = e0 + atomicAdd(&cnt[dl], 1);
        csr[pos] = make_int2(p.x & 0x1FFFF, p.y);
    }
}

// ------- rescale csr in place: w -> nv = dinv[s]*w*dinv[d]; emit dvec row-sums -------

__global__ void __launch_bounds__(256) k_rescale(
        const int* __restrict__ offsets, int2* __restrict__ csr,
        const float* __restrict__ dinv, const float* __restrict__ selfnorm,
        float* __restrict__ dvec) {
    int wid = (blockIdx.x * 256 + threadIdx.x) >> 6;
    int lane = threadIdx.x & 63;
    if (wid >= N_NODES) return;
    int e0 = offsets[wid], e1 = offsets[wid + 1];
    float dvd = dinv[wid];
    float part = 0.0f;
    for (int e = e0 + lane; e < e1; e += 64) {
        int2 p = csr[e];
        float nv = dinv[p.x] * __int_as_float(p.y) * dvd;
        csr[e] = make_int2(p.x, __float_as_int(nv));
        part += nv;
    }
#pragma unroll
    for (int off = 32; off > 0; off >>= 1) part += __shfl_xor(part, off, 64);
    if (lane == 0) dvec[wid] = selfnorm[wid] + part;
}

// ------- fused layer 0: agg (8ch) + matmul 8x64 + relu + stats -------
// block = 32 nodes x 8 lanes. 16-edge windows, next window prefetched
// (software pipeline) so csr latency overlaps the 16 in-flight x-row loads.

__global__ void __launch_bounds__(256) k_aggmm0(
        const float* __restrict__ x, const int* __restrict__ offsets,
        const int2* __restrict__ csr, const float* __restrict__ selfnorm,
        const float* __restrict__ W0, const float* __restrict__ b0,
        bf16_t* __restrict__ rout, float* __restrict__ stats) {
    __shared__ float Wsh[IN_DIM * 64];
    __shared__ float bsh[64];
    __shared__ float sstat[64], sq[64];
    int tid = threadIdx.x;
    for (int i = tid; i < IN_DIM * 64; i += 256) Wsh[i] = W0[i];
    if (tid < 64) { bsh[tid] = b0[tid]; sstat[tid] = 0.0f; sq[tid] = 0.0f; }
    __syncthreads();
    int node = blockIdx.x * 32 + (tid >> 3);
    int ch = tid & 7;
    float acc = selfnorm[node] * x[node * 8 + ch];
    int e0 = offsets[node], e1 = offsets[node + 1];
    int2 pad = make_int2(node, 0);
    int base = e0;
    int2 pA = (base + ch < e1) ? csr[base + ch] : pad;
    int2 pB = (base + 8 + ch < e1) ? csr[base + 8 + ch] : pad;
    while (base < e1) {
        int nb = base + 16;
        int2 nA = pad, nB = pad;
        if (nb < e1) {
            nA = (nb + ch < e1) ? csr[nb + ch] : pad;
            nB = (nb + 8 + ch < e1) ? csr[nb + 8 + ch] : pad;
        }
        int sA[8], sB[8];
        float wA[8], wB[8];
#pragma unroll
        for (int u = 0; u < 8; ++u) {
            sA[u] = __shfl(pA.x, u, 8);
            wA[u] = __int_as_float(__shfl(pA.y, u, 8));
            sB[u] = __shfl(pB.x, u, 8);
            wB[u] = __int_as_float(__shfl(pB.y, u, 8));
        }
        float vA[8], vB[8];
#pragma unroll
        for (int u = 0; u < 8; ++u) vA[u] = x[sA[u] * 8 + ch];
#pragma unroll
        for (int u = 0; u < 8; ++u) vB[u] = x[sB[u] * 8 + ch];
#pragma unroll
        for (int u = 0; u < 8; ++u) acc = fmaf(wA[u], vA[u], acc);
#pragma unroll
        for (int u = 0; u < 8; ++u) acc = fmaf(wB[u], vB[u], acc);
        base = nb;
        pA = nA; pB = nB;
    }
    float a[8];
#pragma unroll
    for (int k = 0; k < 8; ++k) a[k] = __shfl(acc, k, 8);
    unsigned int pk[4];
#pragma unroll
    for (int q = 0; q < 4; ++q) {
        float v0, v1;
#pragma unroll
        for (int h = 0; h < 2; ++h) {
            int c = ch * 8 + 2 * q + h;
            float v = bsh[c];
#pragma unroll
            for (int k = 0; k < 8; ++k) v = fmaf(a[k], Wsh[k * 64 + c], v);
            v = fmaxf(v, 0.0f);
            atomicAdd(&sstat[c], v);
            atomicAdd(&sq[c], v * v);
            if (h == 0) v0 = v; else v1 = v;
        }
        pk[q] = (unsigned int)f2bf(v0) | ((unsigned int)f2bf(v1) << 16);
    }
    *(uint4*)(rout + (size_t)node * 64 + ch * 8) = make_uint4(pk[0], pk[1], pk[2], pk[3]);
    __syncthreads();
    if (tid < 64) {
        int bin = blockIdx.x & 7;
        atomicAdd(&stats[bin * 128 + tid], sstat[tid]);
        atomicAdd(&stats[bin * 128 + 64 + tid], sq[tid]);
    }
}

// ------- fused layer: gather + BN-affine + 64x64 matvec + bias + relu + stats -------
// block = 512 (8 waves, 8 nodes). Gather: lane-parallel CSR window + 8-wide
// broadcast row loads (proven R8 shape). Then affine in-register, per-wave LDS
// round-trip, matvec from LDS-staged W, bf16 store, binned stats.

__global__ void __launch_bounds__(512) k_gmm(
        const bf16_t* __restrict__ t, const int* __restrict__ offsets,
        const int2* __restrict__ csr, const float* __restrict__ selfnorm,
        const float* __restrict__ dvec, const float* __restrict__ statsin,
        const float* __restrict__ gamma, const float* __restrict__ beta,
        const float* __restrict__ W, const float* __restrict__ bias,
        bf16_t* __restrict__ rout, float* __restrict__ statsout) {
    __shared__ float Wsh[64 * 64];
    __shared__ float scs[64], shs[64];
    __shared__ float aw[8][64];
    __shared__ float s1[512], s2[512];
    int tid = threadIdx.x;
    int wv = tid >> 6, lane = tid & 63;
    if (tid < 64) {
        float s = 0.0f, q = 0.0f;
#pragma unroll
        for (int b = 0; b < 8; ++b) {
            s += statsin[b * 128 + tid];
            q += statsin[b * 128 + 64 + tid];
        }
        const float invn = 1.0f / (float)N_NODES;
        float mu = s * invn;
        float var = q * invn - mu * mu;
        float rs = rsqrtf(var + BN_EPS);
        float sc = gamma[tid] * rs;
        scs[tid] = sc;
        shs[tid] = beta[tid] - sc * mu;
    }
    {
        const float4* W4 = (const float4*)W;
        float4* Wsh4 = (float4*)Wsh;
        for (int i = tid; i < 1024; i += 512) Wsh4[i] = W4[i];
    }
    __syncthreads();
    int node = blockIdx.x * 8 + wv;
    float acc = selfnorm[node] * bf2f(t[(size_t)node * 64 + lane]);
    int e0 = offsets[node], e1 = offsets[node + 1];
    for (int base = e0; base < e1; base += 64) {
        int n = e1 - base;
        n = (n > 64) ? 64 : n;
        int2 pe = make_int2(node, 0);  // pad: own row, weight 0
        if (lane < n) pe = csr[base + lane];
        int ng = (n + 7) >> 3;
        for (int g = 0; g < ng; ++g) {
            int j = g * 8;
            int s[8];
            float w[8];
#pragma unroll
            for (int u = 0; u < 8; ++u) {
                s[u] = __shfl(pe.x, j + u, 64);
                w[u] = __int_as_float(__shfl(pe.y, j + u, 64));
            }
            float v[8];
#pragma unroll
            for (int u = 0; u < 8; ++u) v[u] = bf2f(t[(size_t)s[u] * 64 + lane]);
#pragma unroll
            for (int u = 0; u < 8; ++u) acc = fmaf(w[u], v[u], acc);
        }
    }
    // BN affine (of previous layer's stats) then stage for matvec
    float aff = fmaf(acc, scs[lane], dvec[node] * shs[lane]);
    aw[wv][lane] = aff;
    __syncthreads();
    float r = bias[lane];
    for (int k = 0; k < 64; k += 4) {
        float4 a4 = *(const float4*)&aw[wv][k];
        r = fmaf(a4.x, Wsh[(k + 0) * 64 + lane], r);
        r = fmaf(a4.y, Wsh[(k + 1) * 64 + lane], r);
        r = fmaf(a4.z, Wsh[(k + 2) * 64 + lane], r);
        r = fmaf(a4.w, Wsh[(k + 3) * 64 + lane], r);
    }
    r = fmaxf(r, 0.0f);
    rout[(size_t)node * 64 + lane] = f2bf(r);
    s1[tid] = r; s2[tid] = r * r;
    __syncthreads();
    if (tid < 64) {
        float a = 0.0f, q = 0.0f;
#pragma unroll
        for (int j = 0; j < 8; ++j) { a += s1[tid + 64 * j]; q += s2[tid + 64 * j]; }
        int bin = blockIdx.x & 7;
        atomicAdd(&statsout[bin * 128 + tid], a);
        atomicAdd(&statsout[bin * 128 + 64 + tid], q);
    }
}

// ---------------- pooling over sorted batch (run-length local accumulation) ----------------

__global__ void __launch_bounds__(256) k_pool(const int* __restrict__ batch,
                                              const bf16_t* __restrict__ h,
                                              float* __restrict__ pooled,
                                              int* __restrict__ gcount) {
    int c = threadIdx.x & 63;
    int wsub = threadIdx.x >> 6;  // 0..3
    int start = blockIdx.x * POOL_ROWS;
    int end = start + POOL_ROWS; if (end > N_NODES) end = N_NODES;
    int cur = -1, cnt = 0;
    float acc = 0.0f;
    for (int r = start + wsub; r < end; r += 4) {
        int g = batch[r];
        float v = bf2f(h[(size_t)r * 64 + c]);
        if (g != cur) {
            if (cur >= 0) {
                atomicAdd(&pooled[cur * 64 + c], acc);
                if (c == 0) atomicAdd(&gcount[cur], cnt);
            }
            cur = g; acc = 0.0f; cnt = 0;
        }
        acc += v; cnt += 1;
    }
    if (cur >= 0) {
        atomicAdd(&pooled[cur * 64 + c], acc);
        if (c == 0) atomicAdd(&gcount[cur], cnt);
    }
}

// ------- head: BN affine from binned stats folded via counts, mlp, log_softmax -------

__global__ void k_head(const float* __restrict__ pooled, const int* __restrict__ gcount,
                       const float* __restrict__ stats, const float* __restrict__ gamma,
                       const float* __restrict__ beta, const float* __restrict__ w1,
                       const float* __restrict__ b1, const float* __restrict__ w2,
                       const float* __restrict__ b2, float* __restrict__ out) {
    __shared__ float p[64];
    __shared__ float hid[64];
    __shared__ float o[2];
    int g = blockIdx.x, c = threadIdx.x;
    float s = 0.0f, q = 0.0f;
#pragma unroll
    for (int b = 0; b < 8; ++b) {
        s += stats[b * 128 + c];
        q += stats[b * 128 + 64 + c];
    }
    const float invn = 1.0f / (float)N_NODES;
    float mu = s * invn;
    float var = q * invn - mu * mu;
    float rs = rsqrtf(var + BN_EPS);
    float sc = gamma[c] * rs;
    float sh = beta[c] - sc * mu;
    p[c] = sc * pooled[g * 64 + c] + (float)gcount[g] * sh;
    __syncthreads();
    float acc = b1[c];
#pragma unroll
    for (int k = 0; k < 64; ++k) acc += p[k] * w1[k * 64 + c];
    hid[c] = fmaxf(acc, 0.0f);
    __syncthreads();
    if (c < 2) {
        float a = b2[c];
#pragma unroll
        for (int k = 0; k < 64; ++k) a += hid[k] * w2[k * 2 + c];
        o[c] = a;
    }
    __syncthreads();
    if (c == 0) {
        float m = fmaxf(o[0], o[1]);
        float l = m + logf(expf(o[0] - m) + expf(o[1] - m));
        out[g * 2 + 0] = o[0] - l;
        out[g * 2 + 1] = o[1] - l;
    }
}

extern "C" void kernel_launch(void* const* d_in, const int* in_sizes, int n_in,
                              void* d_out, int out_size, void* d_ws, size_t ws_size,
                              hipStream_t stream) {
    const float* x        = (const float*)d_in[0];
    const int*   ei       = (const int*)d_in[1];
    const int*   batch    = (const int*)d_in[2];
    const float* edge_attr= (const float*)d_in[3];
    const float* W0       = (const float*)d_in[4];
    const float* b0       = (const float*)d_in[5];
    const float* Ws       = (const float*)d_in[6];
    const float* bs       = (const float*)d_in[7];
    const float* gammas   = (const float*)d_in[8];
    const float* betas    = (const float*)d_in[9];
    const float* lin1_w   = (const float*)d_in[10];
    const float* lin1_b   = (const float*)d_in[11];
    const float* lin2_w   = (const float*)d_in[12];
    const float* lin2_b   = (const float*)d_in[13];
    float* out = (float*)d_out;

    const int* src = ei;
    const int* dst = ei + N_EDGES;

    // workspace layout (float units). NOTE: N*64 bf16 = 3.2M FLOAT units each.
    float*  ws0      = (float*)d_ws;
    float*  selfnorm = ws0;                             // [0, 100000)
    int*    offsets  = (int*)(ws0 + 100000);            // [100000, 200001], pad to 200004
    float*  dvec     = ws0 + 200004;                    // [200004, 300004)
    int2*   csr      = (int2*)(ws0 + 300004);           // [300004, 2800004)
    bf16_t* rbufA    = (bf16_t*)(ws0 + 2800004);        // [2800004, 6000004)  3.2M fl
    bf16_t* rbufB    = (bf16_t*)(ws0 + 6000004);        // [6000004, 9200004)  3.2M fl
    float*  stats    = ws0 + 9200004;                   // 3*1024
    float*  pooled   = stats + 3 * 1024;                // 16384
    int*    gcount   = (int*)(pooled + NGRAPH * 64);    // 256
    // transient CSR-build aliases:
    //   dinv + bucket arrays live in rbufA (dead before aggmm0 writes rbufA)
    //   ebuf lives in rbufB (dead after k_bsort, before layer-1 writes rbufB)
    float* dinv          = (float*)rbufA;                   // 100000
    int*   bucket_count  = (int*)((float*)rbufA + 100000);  // 64
    int*   bucket_base   = (int*)((float*)rbufA + 100064);  // 64
    int*   bucket_cursor = (int*)((float*)rbufA + 100128);  // 64
    int2*  ebuf          = (int2*)rbufB;                    // 2.5M floats

    const int nblk_seg  = N_NODES / 4;               // 25000 (wave per node)
    const int nblk_mm0  = N_NODES / 32;              // 3125
    const int nblk_gmm  = N_NODES / 8;               // 12500 (512-thread blocks)
    const int nblk_pool = (N_NODES + POOL_ROWS - 1) / POOL_ROWS;  // 782

    hipMemsetAsync(bucket_count, 0, 64 * sizeof(int), stream);
    hipMemsetAsync(stats, 0, (3 * 1024 + NGRAPH * 64 + NGRAPH) * sizeof(float), stream);

    // ---- CSR build: bucket hist -> scan -> bucket fill -> in-bucket sort -> rescale ----
    k_bhist<<<NBLK_B, 256, 0, stream>>>(dst, bucket_count);
    k_bscan<<<1, 64, 0, stream>>>(bucket_count, bucket_base, bucket_cursor, offsets);
    k_bfill<<<NBLK_B, 256, 0, stream>>>(src, dst, (const float2*)edge_attr,
                                        bucket_cursor, ebuf);
    k_bsort<<<NBUCK, 512, 0, stream>>>(bucket_base, ebuf, offsets, csr, dinv, selfnorm);
    k_rescale<<<nblk_seg, 256, 0, stream>>>(offsets, csr, dinv, selfnorm, dvec);

    // ---- layer 0: fused agg8 + mm0 -> r0 (bf16, rbufA) + stats0 ----
    k_aggmm0<<<nblk_mm0, 256, 0, stream>>>(x, offsets, csr, selfnorm, W0, b0, rbufA, stats);

    // ---- layer 1: fused gather + BN0-affine + W1 matvec -> r1 (rbufB) + stats1 ----
    k_gmm<<<nblk_gmm, 512, 0, stream>>>(rbufA, offsets, csr, selfnorm, dvec,
                                        stats, gammas, betas, Ws, bs,
                                        rbufB, stats + 1024);

    // ---- layer 2: fused gather + BN1-affine + W2 matvec -> r2 (rbufA) + stats2 ----
    k_gmm<<<nblk_gmm, 512, 0, stream>>>(rbufB, offsets, csr, selfnorm, dvec,
                                        stats + 1024, gammas + 64, betas + 64,
                                        Ws + 64 * 64, bs + 64,
                                        rbufA, stats + 2048);

    // ---- pool raw r2 + head (BN2 affine folded via counts) ----
    k_pool<<<nblk_pool, 256, 0, stream>>>(batch, rbufA, pooled, gcount);
    k_head<<<NGRAPH, 64, 0, stream>>>(pooled, gcount, stats + 2048,
                                      gammas + 2 * 64, betas + 2 * 64,
                                      lin1_w, lin1_b, lin2_w, lin2_b, out);
}

// Round 13
// 460.836 us; speedup vs baseline: 1.4931x; 1.4931x over previous
//
#include <hip/hip_runtime.h>
#include <math.h>

#define N_NODES 100000
#define N_EDGES 1250000
#define NGRAPH 256
#define IN_DIM 8
#define DIM 64
#define BN_EPS 1e-5f

#define BSHIFT 11
#define BNODES 2048
#define NBUCK 49            // ceil(100000 / 2048)
#define NBLK_B 512
#define CHUNK 2442          // ceil(1250000 / 512)

typedef unsigned short bf16_t;

static __device__ inline float bf2f(bf16_t u) {
    return __uint_as_float(((unsigned int)u) << 16);
}
static __device__ inline bf16_t f2bf(float f) {
    unsigned int b = __float_as_uint(f);
    b += 0x7fffu + ((b >> 16) & 1u);
    return (bf16_t)(b >> 16);
}

// ---------------- coarse bucket histogram (49 buckets, LDS-binned) ----------------

__global__ void __launch_bounds__(256) k_bhist(const int* __restrict__ dst,
                                               int* __restrict__ bucket_count) {
    __shared__ int lh[NBUCK];
    int tid = threadIdx.x;
    if (tid < NBUCK) lh[tid] = 0;
    __syncthreads();
    int e0 = blockIdx.x * CHUNK;
    int e1 = e0 + CHUNK; if (e1 > N_EDGES) e1 = N_EDGES;
    for (int e = e0 + tid; e < e1; e += 256)
        atomicAdd(&lh[dst[e] >> BSHIFT], 1);
    __syncthreads();
    if (tid < NBUCK) atomicAdd(&bucket_count[tid], lh[tid]);
}

// ---------------- bucket base scan (49 entries, trivial) ----------------

__global__ void k_bscan(const int* __restrict__ bucket_count, int* __restrict__ bucket_base,
                        int* __restrict__ bucket_cursor, int* __restrict__ offsets) {
    if (threadIdx.x == 0) {
        int acc = 0;
        for (int b = 0; b < NBUCK; ++b) {
            bucket_base[b] = acc;
            bucket_cursor[b] = acc;
            acc += bucket_count[b];
        }
        offsets[N_NODES] = N_EDGES;
    }
}

// ------- bucket fill: per-block LDS count -> contiguous chunk reservation -> burst writes -------

__global__ void __launch_bounds__(256) k_bfill(const int* __restrict__ src,
                                               const int* __restrict__ dst,
                                               const float2* __restrict__ edge_attr,
                                               int* __restrict__ bucket_cursor,
                                               int2* __restrict__ ebuf) {
    __shared__ int lh[NBUCK], lbase[NBUCK];
    int tid = threadIdx.x;
    if (tid < NBUCK) lh[tid] = 0;
    __syncthreads();
    int e0 = blockIdx.x * CHUNK;
    int e1 = e0 + CHUNK; if (e1 > N_EDGES) e1 = N_EDGES;
    for (int e = e0 + tid; e < e1; e += 256)
        atomicAdd(&lh[dst[e] >> BSHIFT], 1);
    __syncthreads();
    if (tid < NBUCK) {
        lbase[tid] = atomicAdd(&bucket_cursor[tid], lh[tid]);
        lh[tid] = 0;
    }
    __syncthreads();
    for (int e = e0 + tid; e < e1; e += 256) {
        int d = dst[e];
        int b = d >> BSHIFT;
        int pos = lbase[b] + atomicAdd(&lh[b], 1);
        int pk = src[e] | ((d & (BNODES - 1)) << 17);  // src<2^17, dlocal<2^11
        ebuf[pos] = make_int2(pk, __float_as_int(edge_attr[e].y));
    }
}

// ------- bucket sort: exact CSR placement + offsets + dinv/selfnorm, all LDS-local -------

__global__ void __launch_bounds__(512) k_bsort(
        const int* __restrict__ bucket_base, const int2* __restrict__ ebuf,
        int* __restrict__ offsets, int2* __restrict__ csr,
        float* __restrict__ dinv, float* __restrict__ selfnorm) {
    __shared__ int cnt[BNODES];
    __shared__ float wsum[BNODES];
    __shared__ int loff[BNODES];
    __shared__ int tsum[512];
    int tid = threadIdx.x;
    int b = blockIdx.x;
    int nbase = b * BNODES;
    int nend = nbase + BNODES; if (nend > N_NODES) nend = N_NODES;
    int nloc = nend - nbase;
    for (int i = tid; i < BNODES; i += 512) { cnt[i] = 0; wsum[i] = 0.0f; }
    __syncthreads();
    int e0 = bucket_base[b];
    int e1 = (b + 1 < NBUCK) ? bucket_base[b + 1] : N_EDGES;
    for (int e = e0 + tid; e < e1; e += 512) {
        int2 p = ebuf[e];
        int dl = p.x >> 17;
        atomicAdd(&cnt[dl], 1);
        atomicAdd(&wsum[dl], __int_as_float(p.y));
    }
    __syncthreads();
    int b4 = tid * 4;
    int c0 = cnt[b4], c1 = cnt[b4 + 1], c2 = cnt[b4 + 2], c3 = cnt[b4 + 3];
    tsum[tid] = c0 + c1 + c2 + c3;
    __syncthreads();
    for (int off = 1; off < 512; off <<= 1) {
        int add = (tid >= off) ? tsum[tid - off] : 0;
        __syncthreads();
        tsum[tid] += add;
        __syncthreads();
    }
    int excl = tsum[tid] - (c0 + c1 + c2 + c3);
    loff[b4] = excl;
    loff[b4 + 1] = excl + c0;
    loff[b4 + 2] = excl + c0 + c1;
    loff[b4 + 3] = excl + c0 + c1 + c2;
    __syncthreads();
    for (int i = tid; i < nloc; i += 512) {
        offsets[nbase + i] = e0 + loff[i];
        float r = rsqrtf(wsum[i] + 1.0f);  // +1 = self-loop weight
        dinv[nbase + i] = r;
        selfnorm[nbase + i] = r * r;
    }
    for (int i = tid; i < BNODES; i += 512) cnt[i] = loff[i];  // cursor
    __syncthreads();
    for (int e = e0 + tid; e < e1; e += 512) {
        int2 p = ebuf[e];
        int dl = p.x >> 17;
        int pos = e0 + atomicAdd(&cnt[dl], 1);
        csr[pos] = make_int2(p.x & 0x1FFFF, p.y);
    }
}

// ------- rescale csr in place: w -> nv = dinv[s]*w*dinv[d]; emit dvec row-sums -------

__global__ void __launch_bounds__(256) k_rescale(
        const int* __restrict__ offsets, int2* __restrict__ csr,
        const float* __restrict__ dinv, const float* __restrict__ selfnorm,
        float* __restrict__ dvec) {
    int wid = (blockIdx.x * 256 + threadIdx.x) >> 6;
    int lane = threadIdx.x & 63;
    if (wid >= N_NODES) return;
    int e0 = offsets[wid], e1 = offsets[wid + 1];
    float dvd = dinv[wid];
    float part = 0.0f;
    for (int e = e0 + lane; e < e1; e += 64) {
        int2 p = csr[e];
        float nv = dinv[p.x] * __int_as_float(p.y) * dvd;
        csr[e] = make_int2(p.x, __float_as_int(nv));
        part += nv;
    }
#pragma unroll
    for (int off = 32; off > 0; off >>= 1) part += __shfl_xor(part, off, 64);
    if (lane == 0) dvec[wid] = selfnorm[wid] + part;
}

// ------- fused layer 0: agg (8ch) + matmul 8x64 + relu + stats -------
// block = 32 nodes x 8 lanes. 16-edge windows, next window prefetched
// (software pipeline) so csr latency overlaps the 16 in-flight x-row loads.

__global__ void __launch_bounds__(256) k_aggmm0(
        const float* __restrict__ x, const int* __restrict__ offsets,
        const int2* __restrict__ csr, const float* __restrict__ selfnorm,
        const float* __restrict__ W0, const float* __restrict__ b0,
        bf16_t* __restrict__ rout, float* __restrict__ stats) {
    __shared__ float Wsh[IN_DIM * 64];
    __shared__ float bsh[64];
    __shared__ float sstat[64], sq[64];
    int tid = threadIdx.x;
    for (int i = tid; i < IN_DIM * 64; i += 256) Wsh[i] = W0[i];
    if (tid < 64) { bsh[tid] = b0[tid]; sstat[tid] = 0.0f; sq[tid] = 0.0f; }
    __syncthreads();
    int node = blockIdx.x * 32 + (tid >> 3);
    int ch = tid & 7;
    float acc = selfnorm[node] * x[node * 8 + ch];
    int e0 = offsets[node], e1 = offsets[node + 1];
    int2 pad = make_int2(node, 0);
    int base = e0;
    int2 pA = (base + ch < e1) ? csr[base + ch] : pad;
    int2 pB = (base + 8 + ch < e1) ? csr[base + 8 + ch] : pad;
    while (base < e1) {
        int nb = base + 16;
        int2 nA = pad, nB = pad;
        if (nb < e1) {
            nA = (nb + ch < e1) ? csr[nb + ch] : pad;
            nB = (nb + 8 + ch < e1) ? csr[nb + 8 + ch] : pad;
        }
        int sA[8], sB[8];
        float wA[8], wB[8];
#pragma unroll
        for (int u = 0; u < 8; ++u) {
            sA[u] = __shfl(pA.x, u, 8);
            wA[u] = __int_as_float(__shfl(pA.y, u, 8));
            sB[u] = __shfl(pB.x, u, 8);
            wB[u] = __int_as_float(__shfl(pB.y, u, 8));
        }
        float vA[8], vB[8];
#pragma unroll
        for (int u = 0; u < 8; ++u) vA[u] = x[sA[u] * 8 + ch];
#pragma unroll
        for (int u = 0; u < 8; ++u) vB[u] = x[sB[u] * 8 + ch];
#pragma unroll
        for (int u = 0; u < 8; ++u) acc = fmaf(wA[u], vA[u], acc);
#pragma unroll
        for (int u = 0; u < 8; ++u) acc = fmaf(wB[u], vB[u], acc);
        base = nb;
        pA = nA; pB = nB;
    }
    float a[8];
#pragma unroll
    for (int k = 0; k < 8; ++k) a[k] = __shfl(acc, k, 8);
    unsigned int pk[4];
#pragma unroll
    for (int q = 0; q < 4; ++q) {
        float v0, v1;
#pragma unroll
        for (int h = 0; h < 2; ++h) {
            int c = ch * 8 + 2 * q + h;
            float v = bsh[c];
#pragma unroll
            for (int k = 0; k < 8; ++k) v = fmaf(a[k], Wsh[k * 64 + c], v);
            v = fmaxf(v, 0.0f);
            atomicAdd(&sstat[c], v);
            atomicAdd(&sq[c], v * v);
            if (h == 0) v0 = v; else v1 = v;
        }
        pk[q] = (unsigned int)f2bf(v0) | ((unsigned int)f2bf(v1) << 16);
    }
    *(uint4*)(rout + (size_t)node * 64 + ch * 8) = make_uint4(pk[0], pk[1], pk[2], pk[3]);
    __syncthreads();
    if (tid < 64) {
        int bin = blockIdx.x & 7;
        atomicAdd(&stats[bin * 128 + tid], sstat[tid]);
        atomicAdd(&stats[bin * 128 + 64 + tid], sq[tid]);
    }
}

// ------- 64-ch aggregation: lane-parallel CSR + 8-wide pipelined row loads -------

__global__ void __launch_bounds__(256) k_gather64(
        const bf16_t* __restrict__ t, const int* __restrict__ offsets,
        const int2* __restrict__ csr, const float* __restrict__ selfnorm,
        float* __restrict__ agg) {
    int wid = (blockIdx.x * 256 + threadIdx.x) >> 6;
    int lane = threadIdx.x & 63;
    if (wid >= N_NODES) return;
    float acc = selfnorm[wid] * bf2f(t[(size_t)wid * 64 + lane]);
    int e0 = offsets[wid], e1 = offsets[wid + 1];
    for (int base = e0; base < e1; base += 64) {
        int n = e1 - base;
        n = (n > 64) ? 64 : n;
        int2 pe = make_int2(wid, 0);  // pad: own row, weight 0
        if (lane < n) pe = csr[base + lane];
        int ng = (n + 7) >> 3;
        for (int g = 0; g < ng; ++g) {
            int j = g * 8;
            int s[8];
            float w[8];
#pragma unroll
            for (int u = 0; u < 8; ++u) {
                s[u] = __shfl(pe.x, j + u, 64);
                w[u] = __int_as_float(__shfl(pe.y, j + u, 64));
            }
            float v[8];
#pragma unroll
            for (int u = 0; u < 8; ++u) v[u] = bf2f(t[(size_t)s[u] * 64 + lane]);
#pragma unroll
            for (int u = 0; u < 8; ++u) acc = fmaf(w[u], v[u], acc);
        }
    }
    agg[(size_t)wid * 64 + lane] = acc;
}

// ------- mid layer matmul: r' = relu((AGG*sc + dvec*sh) @ W + b), bf16 out, stats -------

__global__ void __launch_bounds__(256) k_mm1(
        const float* __restrict__ agg, const float* __restrict__ dvec,
        const float* __restrict__ statsin, const float* __restrict__ gamma,
        const float* __restrict__ beta, const float* __restrict__ W,
        const float* __restrict__ bias, bf16_t* __restrict__ rout,
        float* __restrict__ statsout) {
    __shared__ float Wsh[64 * 64];
    __shared__ float hsh[32 * 64];
    __shared__ float scs[64], shs[64];
    __shared__ float s1[256], s2[256];
    int tid = threadIdx.x;
    if (tid < 64) {
        float s = 0.0f, q = 0.0f;
#pragma unroll
        for (int b = 0; b < 8; ++b) {
            s += statsin[b * 128 + tid];
            q += statsin[b * 128 + 64 + tid];
        }
        const float invn = 1.0f / (float)N_NODES;
        float mu = s * invn;
        float var = q * invn - mu * mu;
        float rs = rsqrtf(var + BN_EPS);
        float sc = gamma[tid] * rs;
        scs[tid] = sc;
        shs[tid] = beta[tid] - sc * mu;
    }
    {
        const float4* W4 = (const float4*)W;
        float4* Wsh4 = (float4*)Wsh;
        for (int i = tid; i < 1024; i += 256) Wsh4[i] = W4[i];
    }
    __syncthreads();
    int row0 = blockIdx.x * 32;
    {
        const float4* a4 = (const float4*)(agg + (size_t)row0 * 64);
        float4* h4 = (float4*)hsh;
        for (int i = tid; i < 512; i += 256) {
            float4 a = a4[i];
            int kk = (i * 4) & 63;
            int rr = (i * 4) >> 6;
            float dv = dvec[row0 + rr];
            h4[i] = make_float4(a.x * scs[kk] + dv * shs[kk],
                                a.y * scs[kk + 1] + dv * shs[kk + 1],
                                a.z * scs[kk + 2] + dv * shs[kk + 2],
                                a.w * scs[kk + 3] + dv * shs[kk + 3]);
        }
    }
    __syncthreads();
    int c = tid & 63, rsl = tid >> 6;
    float b_c = bias[c];
    float acc[8];
#pragma unroll
    for (int j = 0; j < 8; ++j) acc[j] = 0.0f;
    for (int k = 0; k < 64; k += 4) {
        float w0 = Wsh[(k + 0) * 64 + c];
        float w1 = Wsh[(k + 1) * 64 + c];
        float w2 = Wsh[(k + 2) * 64 + c];
        float w3 = Wsh[(k + 3) * 64 + c];
#pragma unroll
        for (int j = 0; j < 8; ++j) {
            float4 hv = *(const float4*)&hsh[(rsl * 8 + j) * 64 + k];
            acc[j] = fmaf(hv.x, w0, fmaf(hv.y, w1, fmaf(hv.z, w2, fmaf(hv.w, w3, acc[j]))));
        }
    }
    float sum = 0.0f, ssq = 0.0f;
#pragma unroll
    for (int j = 0; j < 8; ++j) {
        float v = fmaxf(acc[j] + b_c, 0.0f);
        rout[(size_t)(row0 + rsl * 8 + j) * 64 + c] = f2bf(v);
        sum += v;
        ssq += v * v;
    }
    s1[tid] = sum; s2[tid] = ssq;
    __syncthreads();
    if (tid < 64) {
        int bin = blockIdx.x & 7;
        atomicAdd(&statsout[bin * 128 + tid],
                  s1[tid] + s1[tid + 64] + s1[tid + 128] + s1[tid + 192]);
        atomicAdd(&statsout[bin * 128 + 64 + tid],
                  s2[tid] + s2[tid + 64] + s2[tid + 128] + s2[tid + 192]);
    }
}

// ------- final layer matmul + fused pooling: r2 never touches global memory -------

__global__ void __launch_bounds__(256) k_mm2(
        const float* __restrict__ agg, const float* __restrict__ dvec,
        const float* __restrict__ statsin, const float* __restrict__ gamma,
        const float* __restrict__ beta, const float* __restrict__ W,
        const float* __restrict__ bias, const int* __restrict__ batch,
        float* __restrict__ pooled, int* __restrict__ gcount,
        float* __restrict__ statsout) {
    __shared__ float Wsh[64 * 64];
    __shared__ float hsh[32 * 64];
    __shared__ float rt[32 * 64];
    __shared__ float scs[64], shs[64];
    __shared__ float s1[256], s2[256];
    __shared__ int sbatch[32];
    int tid = threadIdx.x;
    int row0 = blockIdx.x * 32;
    if (tid < 64) {
        float s = 0.0f, q = 0.0f;
#pragma unroll
        for (int b = 0; b < 8; ++b) {
            s += statsin[b * 128 + tid];
            q += statsin[b * 128 + 64 + tid];
        }
        const float invn = 1.0f / (float)N_NODES;
        float mu = s * invn;
        float var = q * invn - mu * mu;
        float rs = rsqrtf(var + BN_EPS);
        float sc = gamma[tid] * rs;
        scs[tid] = sc;
        shs[tid] = beta[tid] - sc * mu;
    }
    if (tid >= 64 && tid < 96) sbatch[tid - 64] = batch[row0 + tid - 64];
    {
        const float4* W4 = (const float4*)W;
        float4* Wsh4 = (float4*)Wsh;
        for (int i = tid; i < 1024; i += 256) Wsh4[i] = W4[i];
    }
    __syncthreads();
    {
        const float4* a4 = (const float4*)(agg + (size_t)row0 * 64);
        float4* h4 = (float4*)hsh;
        for (int i = tid; i < 512; i += 256) {
            float4 a = a4[i];
            int kk = (i * 4) & 63;
            int rr = (i * 4) >> 6;
            float dv = dvec[row0 + rr];
            h4[i] = make_float4(a.x * scs[kk] + dv * shs[kk],
                                a.y * scs[kk + 1] + dv * shs[kk + 1],
                                a.z * scs[kk + 2] + dv * shs[kk + 2],
                                a.w * scs[kk + 3] + dv * shs[kk + 3]);
        }
    }
    __syncthreads();
    int c = tid & 63, rsl = tid >> 6;
    float b_c = bias[c];
    float acc[8];
#pragma unroll
    for (int j = 0; j < 8; ++j) acc[j] = 0.0f;
    for (int k = 0; k < 64; k += 4) {
        float w0 = Wsh[(k + 0) * 64 + c];
        float w1 = Wsh[(k + 1) * 64 + c];
        float w2 = Wsh[(k + 2) * 64 + c];
        float w3 = Wsh[(k + 3) * 64 + c];
#pragma unroll
        for (int j = 0; j < 8; ++j) {
            float4 hv = *(const float4*)&hsh[(rsl * 8 + j) * 64 + k];
            acc[j] = fmaf(hv.x, w0, fmaf(hv.y, w1, fmaf(hv.z, w2, fmaf(hv.w, w3, acc[j]))));
        }
    }
    float sum = 0.0f, ssq = 0.0f;
#pragma unroll
    for (int j = 0; j < 8; ++j) {
        float v = fmaxf(acc[j] + b_c, 0.0f);
        rt[(rsl * 8 + j) * 64 + c] = v;
        sum += v;
        ssq += v * v;
    }
    s1[tid] = sum; s2[tid] = ssq;
    __syncthreads();
    if (tid < 64) {
        int cur = sbatch[0], cnt = 0;
        float a = 0.0f;
        for (int r = 0; r < 32; ++r) {
            int g = sbatch[r];
            if (g != cur) {
                atomicAdd(&pooled[cur * 64 + c], a);
                if (c == 0) atomicAdd(&gcount[cur], cnt);
                cur = g; a = 0.0f; cnt = 0;
            }
            a += rt[r * 64 + c];
            cnt += 1;
        }
        atomicAdd(&pooled[cur * 64 + c], a);
        if (c == 0) atomicAdd(&gcount[cur], cnt);
        int bin = blockIdx.x & 7;
        atomicAdd(&statsout[bin * 128 + tid],
                  s1[tid] + s1[tid + 64] + s1[tid + 128] + s1[tid + 192]);
        atomicAdd(&statsout[bin * 128 + 64 + tid],
                  s2[tid] + s2[tid + 64] + s2[tid + 128] + s2[tid + 192]);
    }
}

// ------- head: BN affine from binned stats folded via counts, mlp, log_softmax -------

__global__ void k_head(const float* __restrict__ pooled, const int* __restrict__ gcount,
                       const float* __restrict__ stats, const float* __restrict__ gamma,
                       const float* __restrict__ beta, const float* __restrict__ w1,
                       const float* __restrict__ b1, const float* __restrict__ w2,
                       const float* __restrict__ b2, float* __restrict__ out) {
    __shared__ float p[64];
    __shared__ float hid[64];
    __shared__ float o[2];
    int g = blockIdx.x, c = threadIdx.x;
    float s = 0.0f, q = 0.0f;
#pragma unroll
    for (int b = 0; b < 8; ++b) {
        s += stats[b * 128 + c];
        q += stats[b * 128 + 64 + c];
    }
    const float invn = 1.0f / (float)N_NODES;
    float mu = s * invn;
    float var = q * invn - mu * mu;
    float rs = rsqrtf(var + BN_EPS);
    float sc = gamma[c] * rs;
    float sh = beta[c] - sc * mu;
    p[c] = sc * pooled[g * 64 + c] + (float)gcount[g] * sh;
    __syncthreads();
    float acc = b1[c];
#pragma unroll
    for (int k = 0; k < 64; ++k) acc += p[k] * w1[k * 64 + c];
    hid[c] = fmaxf(acc, 0.0f);
    __syncthreads();
    if (c < 2) {
        float a = b2[c];
#pragma unroll
        for (int k = 0; k < 64; ++k) a += hid[k] * w2[k * 2 + c];
        o[c] = a;
    }
    __syncthreads();
    if (c == 0) {
        float m = fmaxf(o[0], o[1]);
        float l = m + logf(expf(o[0] - m) + expf(o[1] - m));
        out[g * 2 + 0] = o[0] - l;
        out[g * 2 + 1] = o[1] - l;
    }
}

extern "C" void kernel_launch(void* const* d_in, const int* in_sizes, int n_in,
                              void* d_out, int out_size, void* d_ws, size_t ws_size,
                              hipStream_t stream) {
    const float* x        = (const float*)d_in[0];
    const int*   ei       = (const int*)d_in[1];
    const int*   batch    = (const int*)d_in[2];
    const float* edge_attr= (const float*)d_in[3];
    const float* W0       = (const float*)d_in[4];
    const float* b0       = (const float*)d_in[5];
    const float* Ws       = (const float*)d_in[6];
    const float* bs       = (const float*)d_in[7];
    const float* gammas   = (const float*)d_in[8];
    const float* betas    = (const float*)d_in[9];
    const float* lin1_w   = (const float*)d_in[10];
    const float* lin1_b   = (const float*)d_in[11];
    const float* lin2_w   = (const float*)d_in[12];
    const float* lin2_b   = (const float*)d_in[13];
    float* out = (float*)d_out;

    const int* src = ei;
    const int* dst = ei + N_EDGES;

    // workspace layout (float units). N*64 bf16 = 3.2M float units.
    float*  ws0      = (float*)d_ws;
    float*  selfnorm = ws0;                             // [0, 100000)
    int*    offsets  = (int*)(ws0 + 100000);            // [100000, 200001], pad to 200004
    float*  dvec     = ws0 + 200004;                    // [200004, 300004)
    int2*   csr      = (int2*)(ws0 + 300004);           // [300004, 2800004)
    bf16_t* rbuf     = (bf16_t*)(ws0 + 2800004);        // [2800004, 6000004)  bf16 N*64
    float*  aggbuf   = ws0 + 6000004;                   // [6000004, 12400004) fp32 N*64
    float*  stats    = aggbuf + (size_t)N_NODES * 64;   // 3*1024
    float*  pooled   = stats + 3 * 1024;                // 16384
    int*    gcount   = (int*)(pooled + NGRAPH * 64);    // 256
    // transient CSR-build aliases inside aggbuf (all dead before gather#1 writes it)
    float* dinv          = aggbuf;                      // 100000
    int*   bucket_count  = (int*)(aggbuf + 100000);     // 64
    int*   bucket_base   = (int*)(aggbuf + 100064);     // 64
    int*   bucket_cursor = (int*)(aggbuf + 100128);     // 64
    int2*  ebuf          = (int2*)(aggbuf + 200000);    // 2.5M floats

    const int nblk_g64 = N_NODES * 64 / 256;         // 25000
    const int nblk_seg = N_NODES / 4;                // 25000 (wave per node)
    const int nblk_mm = N_NODES / 32;                // 3125

    hipMemsetAsync(bucket_count, 0, 64 * sizeof(int), stream);
    hipMemsetAsync(stats, 0, (3 * 1024 + NGRAPH * 64 + NGRAPH) * sizeof(float), stream);

    // ---- CSR build: bucket hist -> scan -> bucket fill -> in-bucket sort -> rescale ----
    k_bhist<<<NBLK_B, 256, 0, stream>>>(dst, bucket_count);
    k_bscan<<<1, 64, 0, stream>>>(bucket_count, bucket_base, bucket_cursor, offsets);
    k_bfill<<<NBLK_B, 256, 0, stream>>>(src, dst, (const float2*)edge_attr,
                                        bucket_cursor, ebuf);
    k_bsort<<<NBUCK, 512, 0, stream>>>(bucket_base, ebuf, offsets, csr, dinv, selfnorm);
    k_rescale<<<nblk_seg, 256, 0, stream>>>(offsets, csr, dinv, selfnorm, dvec);

    // ---- layer 0: fused agg8 + mm0 -> r0 (bf16) + stats0 ----
    k_aggmm0<<<nblk_mm, 256, 0, stream>>>(x, offsets, csr, selfnorm, W0, b0, rbuf, stats);

    // ---- layer 1: gather + mm -> r1 (bf16) + stats1 ----
    k_gather64<<<nblk_g64, 256, 0, stream>>>(rbuf, offsets, csr, selfnorm, aggbuf);
    k_mm1<<<nblk_mm, 256, 0, stream>>>(aggbuf, dvec, stats, gammas, betas,
                                       Ws, bs, rbuf, stats + 1024);

    // ---- layer 2: gather + mm with fused pooling (r2 stays on-chip) ----
    k_gather64<<<nblk_g64, 256, 0, stream>>>(rbuf, offsets, csr, selfnorm, aggbuf);
    k_mm2<<<nblk_mm, 256, 0, stream>>>(aggbuf, dvec, stats + 1024, gammas + 64, betas + 64,
                                       Ws + 64 * 64, bs + 64, batch, pooled, gcount,
                                       stats + 2048);

    // ---- head ----
    k_head<<<NGRAPH, 64, 0, stream>>>(pooled, gcount, stats + 2048,
                                      gammas + 2 * 64, betas + 2 * 64,
                                      lin1_w, lin1_b, lin2_w, lin2_b, out);
}

// Round 14
// 399.148 us; speedup vs baseline: 1.7238x; 1.1545x over previous
//
#include <hip/hip_runtime.h>
#include <math.h>

#define N_NODES 100000
#define N_EDGES 1250000
#define NGRAPH 256
#define IN_DIM 8
#define DIM 64
#define BN_EPS 1e-5f

#define BSHIFT 11
#define BNODES 2048
#define NBUCK 49            // ceil(100000 / 2048)
#define NBLK_B 512
#define CHUNK 2442          // ceil(1250000 / 512)
#define POOL_ROWS 128
#define NTILES 3125         // N_NODES / 32

typedef unsigned short bf16_t;

static __device__ inline float bf2f(bf16_t u) {
    return __uint_as_float(((unsigned int)u) << 16);
}
static __device__ inline bf16_t f2bf(float f) {
    unsigned int b = __float_as_uint(f);
    b += 0x7fffu + ((b >> 16) & 1u);
    return (bf16_t)(b >> 16);
}

// ---------------- coarse bucket histogram (49 buckets, LDS-binned) ----------------

__global__ void __launch_bounds__(256) k_bhist(const int* __restrict__ dst,
                                               int* __restrict__ bucket_count) {
    __shared__ int lh[NBUCK];
    int tid = threadIdx.x;
    if (tid < NBUCK) lh[tid] = 0;
    __syncthreads();
    int e0 = blockIdx.x * CHUNK;
    int e1 = e0 + CHUNK; if (e1 > N_EDGES) e1 = N_EDGES;
    for (int e = e0 + tid; e < e1; e += 256)
        atomicAdd(&lh[dst[e] >> BSHIFT], 1);
    __syncthreads();
    if (tid < NBUCK) atomicAdd(&bucket_count[tid], lh[tid]);
}

// ---------------- bucket base scan (49 entries, trivial) ----------------

__global__ void k_bscan(const int* __restrict__ bucket_count, int* __restrict__ bucket_base,
                        int* __restrict__ bucket_cursor, int* __restrict__ offsets) {
    if (threadIdx.x == 0) {
        int acc = 0;
        for (int b = 0; b < NBUCK; ++b) {
            bucket_base[b] = acc;
            bucket_cursor[b] = acc;
            acc += bucket_count[b];
        }
        offsets[N_NODES] = N_EDGES;
    }
}

// ------- bucket fill: per-block LDS count -> contiguous chunk reservation -> burst writes -------

__global__ void __launch_bounds__(256) k_bfill(const int* __restrict__ src,
                                               const int* __restrict__ dst,
                                               const float2* __restrict__ edge_attr,
                                               int* __restrict__ bucket_cursor,
                                               int2* __restrict__ ebuf) {
    __shared__ int lh[NBUCK], lbase[NBUCK];
    int tid = threadIdx.x;
    if (tid < NBUCK) lh[tid] = 0;
    __syncthreads();
    int e0 = blockIdx.x * CHUNK;
    int e1 = e0 + CHUNK; if (e1 > N_EDGES) e1 = N_EDGES;
    for (int e = e0 + tid; e < e1; e += 256)
        atomicAdd(&lh[dst[e] >> BSHIFT], 1);
    __syncthreads();
    if (tid < NBUCK) {
        lbase[tid] = atomicAdd(&bucket_cursor[tid], lh[tid]);
        lh[tid] = 0;
    }
    __syncthreads();
    for (int e = e0 + tid; e < e1; e += 256) {
        int d = dst[e];
        int b = d >> BSHIFT;
        int pos = lbase[b] + atomicAdd(&lh[b], 1);
        int pk = src[e] | ((d & (BNODES - 1)) << 17);  // src<2^17, dlocal<2^11
        ebuf[pos] = make_int2(pk, __float_as_int(edge_attr[e].y));
    }
}

// ------- bucket sort: exact CSR placement (raw w) + offsets + dinv, all LDS-local -------

__global__ void __launch_bounds__(512) k_bsort(
        const int* __restrict__ bucket_base, const int2* __restrict__ ebuf,
        int* __restrict__ offsets, int2* __restrict__ csr,
        float* __restrict__ dinv) {
    __shared__ int cnt[BNODES];
    __shared__ float wsum[BNODES];
    __shared__ int loff[BNODES];
    __shared__ int tsum[512];
    int tid = threadIdx.x;
    int b = blockIdx.x;
    int nbase = b * BNODES;
    int nend = nbase + BNODES; if (nend > N_NODES) nend = N_NODES;
    int nloc = nend - nbase;
    for (int i = tid; i < BNODES; i += 512) { cnt[i] = 0; wsum[i] = 0.0f; }
    __syncthreads();
    int e0 = bucket_base[b];
    int e1 = (b + 1 < NBUCK) ? bucket_base[b + 1] : N_EDGES;
    for (int e = e0 + tid; e < e1; e += 512) {
        int2 p = ebuf[e];
        int dl = p.x >> 17;
        atomicAdd(&cnt[dl], 1);
        atomicAdd(&wsum[dl], __int_as_float(p.y));
    }
    __syncthreads();
    int b4 = tid * 4;
    int c0 = cnt[b4], c1 = cnt[b4 + 1], c2 = cnt[b4 + 2], c3 = cnt[b4 + 3];
    tsum[tid] = c0 + c1 + c2 + c3;
    __syncthreads();
    for (int off = 1; off < 512; off <<= 1) {
        int add = (tid >= off) ? tsum[tid - off] : 0;
        __syncthreads();
        tsum[tid] += add;
        __syncthreads();
    }
    int excl = tsum[tid] - (c0 + c1 + c2 + c3);
    loff[b4] = excl;
    loff[b4 + 1] = excl + c0;
    loff[b4 + 2] = excl + c0 + c1;
    loff[b4 + 3] = excl + c0 + c1 + c2;
    __syncthreads();
    for (int i = tid; i < nloc; i += 512) {
        offsets[nbase + i] = e0 + loff[i];
        dinv[nbase + i] = rsqrtf(wsum[i] + 1.0f);  // +1 = self-loop weight
    }
    for (int i = tid; i < BNODES; i += 512) cnt[i] = loff[i];  // cursor
    __syncthreads();
    for (int e = e0 + tid; e < e1; e += 512) {
        int2 p = ebuf[e];
        int dl = p.x >> 17;
        int pos = e0 + atomicAdd(&cnt[dl], 1);
        csr[pos] = make_int2(p.x & 0x1FFFF, p.y);  // (src, raw w)
    }
}

// ------- mm0: u' = dinv ∘ (x @ W0), bf16 out (32 rows/block) -------

__global__ void __launch_bounds__(256) k_mm0(
        const float* __restrict__ x, const float* __restrict__ dinv,
        const float* __restrict__ W0, bf16_t* __restrict__ out) {
    __shared__ float Wsh[IN_DIM * 64];
    __shared__ float hsh[32 * IN_DIM];
    __shared__ float din[32];
    int tid = threadIdx.x;
    for (int i = tid; i < IN_DIM * 64; i += 256) Wsh[i] = W0[i];
    int row0 = blockIdx.x * 32;
    if (tid < 32 * IN_DIM) hsh[tid] = x[row0 * IN_DIM + tid];
    if (tid >= 224) din[tid - 224] = dinv[row0 + tid - 224];
    __syncthreads();
    int c = tid & 63, rsl = tid >> 6;
#pragma unroll
    for (int j = 0; j < 8; ++j) {
        int r = rsl * 8 + j;
        float acc = 0.0f;
#pragma unroll
        for (int k = 0; k < IN_DIM; ++k) acc = fmaf(hsh[r * IN_DIM + k], Wsh[k * 64 + c], acc);
        out[(size_t)(row0 + r) * 64 + c] = f2bf(acc * din[r]);
    }
}

// ------- affmm: u' = dinv ∘ (affine(r) @ W), bf16 in/out (32 rows/block) -------

__global__ void __launch_bounds__(256) k_affmm(
        const bf16_t* __restrict__ r, const float* __restrict__ dinv,
        const float* __restrict__ statsin, const float* __restrict__ gamma,
        const float* __restrict__ beta, const float* __restrict__ W,
        bf16_t* __restrict__ out) {
    __shared__ float Wsh[64 * 64];
    __shared__ float hsh[32 * 64];
    __shared__ float scs[64], shs[64];
    __shared__ float din[32];
    int tid = threadIdx.x;
    if (tid < 64) {
        float s = 0.0f, q = 0.0f;
#pragma unroll
        for (int b = 0; b < 8; ++b) {
            s += statsin[b * 128 + tid];
            q += statsin[b * 128 + 64 + tid];
        }
        const float invn = 1.0f / (float)N_NODES;
        float mu = s * invn;
        float var = q * invn - mu * mu;
        float rs = rsqrtf(var + BN_EPS);
        float sc = gamma[tid] * rs;
        scs[tid] = sc;
        shs[tid] = beta[tid] - sc * mu;
    }
    {
        const float4* W4 = (const float4*)W;
        float4* Wsh4 = (float4*)Wsh;
        for (int i = tid; i < 1024; i += 256) Wsh4[i] = W4[i];
    }
    int row0 = blockIdx.x * 32;
    if (tid >= 224) din[tid - 224] = dinv[row0 + tid - 224];
    __syncthreads();
    {
        const ushort2* r2 = (const ushort2*)(r + (size_t)row0 * 64);
        for (int i = tid; i < 1024; i += 256) {
            ushort2 u = r2[i];
            int base = 2 * i;
            int kk = base & 63;
            hsh[base] = fmaf(bf2f(u.x), scs[kk], shs[kk]);
            hsh[base + 1] = fmaf(bf2f(u.y), scs[kk + 1], shs[kk + 1]);
        }
    }
    __syncthreads();
    int c = tid & 63, rsl = tid >> 6;
    float acc[8];
#pragma unroll
    for (int j = 0; j < 8; ++j) acc[j] = 0.0f;
    for (int k = 0; k < 64; k += 4) {
        float w0 = Wsh[(k + 0) * 64 + c];
        float w1 = Wsh[(k + 1) * 64 + c];
        float w2 = Wsh[(k + 2) * 64 + c];
        float w3 = Wsh[(k + 3) * 64 + c];
#pragma unroll
        for (int j = 0; j < 8; ++j) {
            float4 hv = *(const float4*)&hsh[(rsl * 8 + j) * 64 + k];
            acc[j] = fmaf(hv.x, w0, fmaf(hv.y, w1, fmaf(hv.z, w2, fmaf(hv.w, w3, acc[j]))));
        }
    }
#pragma unroll
    for (int j = 0; j < 8; ++j) {
        int rr = rsl * 8 + j;
        out[(size_t)(row0 + rr) * 64 + c] = f2bf(acc[j] * din[rr]);
    }
}

// ------- gather: r = relu(dinv[d]*(u'[d] + sum w*u'[s]) + bias), bf16 in/out -------
// one wave per node; lane-parallel CSR window + 8-wide broadcast row loads (R8 shape).

__global__ void __launch_bounds__(256) k_gather(
        const bf16_t* __restrict__ t, const int* __restrict__ offsets,
        const int2* __restrict__ csr, const float* __restrict__ dinv,
        const float* __restrict__ bias, bf16_t* __restrict__ rout) {
    int wid = (blockIdx.x * 256 + threadIdx.x) >> 6;
    int lane = threadIdx.x & 63;
    if (wid >= N_NODES) return;
    float acc = bf2f(t[(size_t)wid * 64 + lane]);  // self edge, w=1
    int e0 = offsets[wid], e1 = offsets[wid + 1];
    for (int base = e0; base < e1; base += 64) {
        int n = e1 - base;
        n = (n > 64) ? 64 : n;
        int2 pe = make_int2(wid, 0);  // pad: own row, weight 0
        if (lane < n) pe = csr[base + lane];
        int ng = (n + 7) >> 3;
        for (int g = 0; g < ng; ++g) {
            int j = g * 8;
            int s[8];
            float w[8];
#pragma unroll
            for (int u = 0; u < 8; ++u) {
                s[u] = __shfl(pe.x, j + u, 64);
                w[u] = __int_as_float(__shfl(pe.y, j + u, 64));
            }
            float v[8];
#pragma unroll
            for (int u = 0; u < 8; ++u) v[u] = bf2f(t[(size_t)s[u] * 64 + lane]);
#pragma unroll
            for (int u = 0; u < 8; ++u) acc = fmaf(w[u], v[u], acc);
        }
    }
    float rv = fmaxf(fmaf(acc, dinv[wid], bias[lane]), 0.0f);
    rout[(size_t)wid * 64 + lane] = f2bf(rv);
}

// ------- BN stats of a bf16 feature array, 8-binned (grid-stride, 1024 blocks) -------

__global__ void __launch_bounds__(256) k_bnstats(const bf16_t* __restrict__ r,
                                                 float* __restrict__ statsout) {
    __shared__ float s1[256], s2[256];
    int tid = threadIdx.x;
    int c = tid & 63, rsl = tid >> 6;
    float sum = 0.0f, ssq = 0.0f;
    for (int tile = blockIdx.x; tile < NTILES; tile += gridDim.x) {
        int row0 = tile * 32;
#pragma unroll
        for (int j = 0; j < 8; ++j) {
            float v = bf2f(r[(size_t)(row0 + rsl * 8 + j) * 64 + c]);
            sum += v;
            ssq += v * v;
        }
    }
    s1[tid] = sum; s2[tid] = ssq;
    __syncthreads();
    if (tid < 64) {
        int bin = blockIdx.x & 7;
        atomicAdd(&statsout[bin * 128 + tid],
                  s1[tid] + s1[tid + 64] + s1[tid + 128] + s1[tid + 192]);
        atomicAdd(&statsout[bin * 128 + 64 + tid],
                  s2[tid] + s2[tid + 64] + s2[tid + 128] + s2[tid + 192]);
    }
}

// ------- pooling over sorted batch (run-length) + fused layer-2 BN stats -------

__global__ void __launch_bounds__(256) k_pool(const int* __restrict__ batch,
                                              const bf16_t* __restrict__ h,
                                              float* __restrict__ pooled,
                                              int* __restrict__ gcount,
                                              float* __restrict__ statsout) {
    __shared__ float s1[256], s2[256];
    int tid = threadIdx.x;
    int c = tid & 63;
    int wsub = tid >> 6;  // 0..3
    int start = blockIdx.x * POOL_ROWS;
    int end = start + POOL_ROWS; if (end > N_NODES) end = N_NODES;
    int cur = -1, cnt = 0;
    float acc = 0.0f, sum = 0.0f, ssq = 0.0f;
    for (int r = start + wsub; r < end; r += 4) {
        int g = batch[r];
        float v = bf2f(h[(size_t)r * 64 + c]);
        if (g != cur) {
            if (cur >= 0) {
                atomicAdd(&pooled[cur * 64 + c], acc);
                if (c == 0) atomicAdd(&gcount[cur], cnt);
            }
            cur = g; acc = 0.0f; cnt = 0;
        }
        acc += v; cnt += 1;
        sum += v; ssq += v * v;
    }
    if (cur >= 0) {
        atomicAdd(&pooled[cur * 64 + c], acc);
        if (c == 0) atomicAdd(&gcount[cur], cnt);
    }
    s1[tid] = sum; s2[tid] = ssq;
    __syncthreads();
    if (tid < 64) {
        int bin = blockIdx.x & 7;
        atomicAdd(&statsout[bin * 128 + tid],
                  s1[tid] + s1[tid + 64] + s1[tid + 128] + s1[tid + 192]);
        atomicAdd(&statsout[bin * 128 + 64 + tid],
                  s2[tid] + s2[tid + 64] + s2[tid + 128] + s2[tid + 192]);
    }
}

// ------- head: BN affine from binned stats folded via counts, mlp, log_softmax -------

__global__ void k_head(const float* __restrict__ pooled, const int* __restrict__ gcount,
                       const float* __restrict__ stats, const float* __restrict__ gamma,
                       const float* __restrict__ beta, const float* __restrict__ w1,
                       const float* __restrict__ b1, const float* __restrict__ w2,
                       const float* __restrict__ b2, float* __restrict__ out) {
    __shared__ float p[64];
    __shared__ float hid[64];
    __shared__ float o[2];
    int g = blockIdx.x, c = threadIdx.x;
    float s = 0.0f, q = 0.0f;
#pragma unroll
    for (int b = 0; b < 8; ++b) {
        s += stats[b * 128 + c];
        q += stats[b * 128 + 64 + c];
    }
    const float invn = 1.0f / (float)N_NODES;
    float mu = s * invn;
    float var = q * invn - mu * mu;
    float rs = rsqrtf(var + BN_EPS);
    float sc = gamma[c] * rs;
    float sh = beta[c] - sc * mu;
    p[c] = sc * pooled[g * 64 + c] + (float)gcount[g] * sh;
    __syncthreads();
    float acc = b1[c];
#pragma unroll
    for (int k = 0; k < 64; ++k) acc += p[k] * w1[k * 64 + c];
    hid[c] = fmaxf(acc, 0.0f);
    __syncthreads();
    if (c < 2) {
        float a = b2[c];
#pragma unroll
        for (int k = 0; k < 64; ++k) a += hid[k] * w2[k * 2 + c];
        o[c] = a;
    }
    __syncthreads();
    if (c == 0) {
        float m = fmaxf(o[0], o[1]);
        float l = m + logf(expf(o[0] - m) + expf(o[1] - m));
        out[g * 2 + 0] = o[0] - l;
        out[g * 2 + 1] = o[1] - l;
    }
}

extern "C" void kernel_launch(void* const* d_in, const int* in_sizes, int n_in,
                              void* d_out, int out_size, void* d_ws, size_t ws_size,
                              hipStream_t stream) {
    const float* x        = (const float*)d_in[0];
    const int*   ei       = (const int*)d_in[1];
    const int*   batch    = (const int*)d_in[2];
    const float* edge_attr= (const float*)d_in[3];
    const float* W0       = (const float*)d_in[4];
    const float* b0       = (const float*)d_in[5];
    const float* Ws       = (const float*)d_in[6];
    const float* bs       = (const float*)d_in[7];
    const float* gammas   = (const float*)d_in[8];
    const float* betas    = (const float*)d_in[9];
    const float* lin1_w   = (const float*)d_in[10];
    const float* lin1_b   = (const float*)d_in[11];
    const float* lin2_w   = (const float*)d_in[12];
    const float* lin2_b   = (const float*)d_in[13];
    float* out = (float*)d_out;

    const int* src = ei;
    const int* dst = ei + N_EDGES;

    // workspace layout (float units). N*64 bf16 = 3.2M float units per buffer.
    float*  ws0      = (float*)d_ws;
    float*  dinv     = ws0;                             // [0, 100004)
    int*    offsets  = (int*)(ws0 + 100004);            // 100001 ints, pad to 200008
    int2*   csr      = (int2*)(ws0 + 200008);           // [200008, 2700008)
    bf16_t* tB       = (bf16_t*)(ws0 + 2700008);        // [2700008, 5900008)  u' rows
    bf16_t* rA       = (bf16_t*)(ws0 + 5900008);        // [5900008, 9100008)  r rows
    float*  stats    = ws0 + 9100008;                   // 3*1024
    float*  pooled   = stats + 3 * 1024;                // 16384
    int*    gcount   = (int*)(pooled + NGRAPH * 64);    // 256
    // transient CSR-build aliases:
    //   ebuf in rA (dead after bsort; rA first written by gather0)
    //   bucket arrays in tB (dead before mm0 writes tB)
    int2*  ebuf          = (int2*)rA;                       // 2.5M floats
    int*   bucket_count  = (int*)tB;                        // 64
    int*   bucket_base   = (int*)((float*)tB + 64);         // 64
    int*   bucket_cursor = (int*)((float*)tB + 128);        // 64

    const int nblk_g   = N_NODES * 64 / 256;   // 25000 (wave per node)
    const int nblk_mm  = NTILES;               // 3125

    hipMemsetAsync(bucket_count, 0, 64 * sizeof(int), stream);
    hipMemsetAsync(stats, 0, (3 * 1024 + NGRAPH * 64 + NGRAPH) * sizeof(float), stream);

    // ---- CSR build (raw w): bucket hist -> scan -> fill -> in-bucket sort ----
    k_bhist<<<NBLK_B, 256, 0, stream>>>(dst, bucket_count);
    k_bscan<<<1, 64, 0, stream>>>(bucket_count, bucket_base, bucket_cursor, offsets);
    k_bfill<<<NBLK_B, 256, 0, stream>>>(src, dst, (const float2*)edge_attr,
                                        bucket_cursor, ebuf);
    k_bsort<<<NBUCK, 512, 0, stream>>>(bucket_base, ebuf, offsets, csr, dinv);

    // ---- layer 0: mm0 (dinv∘(x@W0)) -> gather(+b0,relu) -> r0 ----
    k_mm0<<<nblk_mm, 256, 0, stream>>>(x, dinv, W0, tB);
    k_gather<<<nblk_g, 256, 0, stream>>>(tB, offsets, csr, dinv, b0, rA);
    k_bnstats<<<1024, 256, 0, stream>>>(rA, stats);

    // ---- layer 1 ----
    k_affmm<<<nblk_mm, 256, 0, stream>>>(rA, dinv, stats, gammas, betas, Ws, tB);
    k_gather<<<nblk_g, 256, 0, stream>>>(tB, offsets, csr, dinv, bs, rA);
    k_bnstats<<<1024, 256, 0, stream>>>(rA, stats + 1024);

    // ---- layer 2 ----
    k_affmm<<<nblk_mm, 256, 0, stream>>>(rA, dinv, stats + 1024, gammas + 64, betas + 64,
                                         Ws + 64 * 64, tB);
    k_gather<<<nblk_g, 256, 0, stream>>>(tB, offsets, csr, dinv, bs + 64, rA);

    // ---- pool (+ fused layer-2 stats) + head ----
    k_pool<<<(N_NODES + POOL_ROWS - 1) / POOL_ROWS, 256, 0, stream>>>(
        batch, rA, pooled, gcount, stats + 2048);
    k_head<<<NGRAPH, 64, 0, stream>>>(pooled, gcount, stats + 2048,
                                      gammas + 2 * 64, betas + 2 * 64,
                                      lin1_w, lin1_b, lin2_w, lin2_b, out);
}

// Round 15
// 362.625 us; speedup vs baseline: 1.8975x; 1.1007x over previous
//
#include <hip/hip_runtime.h>
#include <math.h>

#define N_NODES 100000
#define N_EDGES 1250000
#define NGRAPH 256
#define IN_DIM 8
#define DIM 64
#define BN_EPS 1e-5f

#define BSHIFT 9
#define BNODES 512
#define NBUCK 196           // ceil(100000 / 512)
#define BCAP 8192           // fixed bucket capacity (mean 6400, +22 sigma)
#define NBLK_B 512
#define CHUNK 2442          // ceil(1250000 / 512)
#define POOL_ROWS 128
#define NTILES 3125         // N_NODES / 32

typedef unsigned short bf16_t;

static __device__ inline float bf2f(bf16_t u) {
    return __uint_as_float(((unsigned int)u) << 16);
}
static __device__ inline bf16_t f2bf(float f) {
    unsigned int b = __float_as_uint(f);
    b += 0x7fffu + ((b >> 16) & 1u);
    return (bf16_t)(b >> 16);
}

// ---------------- init bucket cursors to fixed bases ----------------

__global__ void k_init(int* __restrict__ bucket_cursor) {
    int i = threadIdx.x;
    if (i < NBUCK) bucket_cursor[i] = i * BCAP;
}

// ------- bucket fill: per-block LDS count -> chunk reservation -> burst writes -------

__global__ void __launch_bounds__(256) k_bfill(const int* __restrict__ src,
                                               const int* __restrict__ dst,
                                               const float2* __restrict__ edge_attr,
                                               int* __restrict__ bucket_cursor,
                                               int2* __restrict__ ebuf) {
    __shared__ int lh[NBUCK], lbase[NBUCK];
    int tid = threadIdx.x;
    if (tid < NBUCK) lh[tid] = 0;
    __syncthreads();
    int e0 = blockIdx.x * CHUNK;
    int e1 = e0 + CHUNK; if (e1 > N_EDGES) e1 = N_EDGES;
    for (int e = e0 + tid; e < e1; e += 256)
        atomicAdd(&lh[dst[e] >> BSHIFT], 1);
    __syncthreads();
    if (tid < NBUCK) {
        lbase[tid] = atomicAdd(&bucket_cursor[tid], lh[tid]);
        lh[tid] = 0;
    }
    __syncthreads();
    for (int e = e0 + tid; e < e1; e += 256) {
        int d = dst[e];
        int b = d >> BSHIFT;
        int pos = lbase[b] + atomicAdd(&lh[b], 1);
        int pk = src[e] | ((d & (BNODES - 1)) << 17);  // src<2^17, dlocal<2^9
        ebuf[pos] = make_int2(pk, __float_as_int(edge_attr[e].y));
    }
}

// ------- bucket sort: CSR placement (raw w) + offsets/ends + dinv, LDS-local -------
// one block (512 thr) per 512-node bucket; 1:1 thread:node scan.

__global__ void __launch_bounds__(512) k_bsort(
        const int* __restrict__ bucket_cursor, const int2* __restrict__ ebuf,
        int* __restrict__ offsets, int* __restrict__ ends, int2* __restrict__ csr,
        float* __restrict__ dinv) {
    __shared__ int cnt[BNODES];
    __shared__ float wsum[BNODES];
    __shared__ int loff[BNODES];
    __shared__ int tsum[BNODES];
    int tid = threadIdx.x;
    int b = blockIdx.x;
    int nbase = b * BNODES;
    int nloc = N_NODES - nbase; if (nloc > BNODES) nloc = BNODES;
    cnt[tid] = 0; wsum[tid] = 0.0f;
    __syncthreads();
    int e0 = b * BCAP;
    int ecnt = bucket_cursor[b] - e0;
    for (int e = e0 + tid; e < e0 + ecnt; e += 512) {
        int2 p = ebuf[e];
        int dl = p.x >> 17;
        atomicAdd(&cnt[dl], 1);
        atomicAdd(&wsum[dl], __int_as_float(p.y));
    }
    __syncthreads();
    int myc = cnt[tid];
    tsum[tid] = myc;
    __syncthreads();
    for (int off = 1; off < 512; off <<= 1) {
        int add = (tid >= off) ? tsum[tid - off] : 0;
        __syncthreads();
        tsum[tid] += add;
        __syncthreads();
    }
    int excl = tsum[tid] - myc;
    loff[tid] = excl;
    if (tid < nloc) {
        offsets[nbase + tid] = e0 + excl;
        ends[nbase + tid] = e0 + excl + myc;
        dinv[nbase + tid] = rsqrtf(wsum[tid] + 1.0f);  // +1 = self-loop weight
    }
    cnt[tid] = excl;  // cursor
    __syncthreads();
    for (int e = e0 + tid; e < e0 + ecnt; e += 512) {
        int2 p = ebuf[e];
        int dl = p.x >> 17;
        int pos = e0 + atomicAdd(&cnt[dl], 1);
        csr[pos] = make_int2(p.x & 0x1FFFF, p.y);  // (src, raw w)
    }
}

// ------- mm0: u' = dinv ∘ (x @ W0), bf16 out (32 rows/block) -------

__global__ void __launch_bounds__(256) k_mm0(
        const float* __restrict__ x, const float* __restrict__ dinv,
        const float* __restrict__ W0, bf16_t* __restrict__ out) {
    __shared__ float Wsh[IN_DIM * 64];
    __shared__ float hsh[32 * IN_DIM];
    __shared__ float din[32];
    int tid = threadIdx.x;
    for (int i = tid; i < IN_DIM * 64; i += 256) Wsh[i] = W0[i];
    int row0 = blockIdx.x * 32;
    if (tid < 32 * IN_DIM) hsh[tid] = x[row0 * IN_DIM + tid];
    if (tid >= 224) din[tid - 224] = dinv[row0 + tid - 224];
    __syncthreads();
    int c = tid & 63, rsl = tid >> 6;
#pragma unroll
    for (int j = 0; j < 8; ++j) {
        int r = rsl * 8 + j;
        float acc = 0.0f;
#pragma unroll
        for (int k = 0; k < IN_DIM; ++k) acc = fmaf(hsh[r * IN_DIM + k], Wsh[k * 64 + c], acc);
        out[(size_t)(row0 + r) * 64 + c] = f2bf(acc * din[r]);
    }
}

// ------- affmm: u' = dinv ∘ (affine(r) @ W), bf16 in/out (32 rows/block) -------

__global__ void __launch_bounds__(256) k_affmm(
        const bf16_t* __restrict__ r, const float* __restrict__ dinv,
        const float* __restrict__ statsin, const float* __restrict__ gamma,
        const float* __restrict__ beta, const float* __restrict__ W,
        bf16_t* __restrict__ out) {
    __shared__ float Wsh[64 * 64];
    __shared__ float hsh[32 * 64];
    __shared__ float scs[64], shs[64];
    __shared__ float din[32];
    int tid = threadIdx.x;
    if (tid < 64) {
        float s = 0.0f, q = 0.0f;
#pragma unroll
        for (int b = 0; b < 8; ++b) {
            s += statsin[b * 128 + tid];
            q += statsin[b * 128 + 64 + tid];
        }
        const float invn = 1.0f / (float)N_NODES;
        float mu = s * invn;
        float var = q * invn - mu * mu;
        float rs = rsqrtf(var + BN_EPS);
        float sc = gamma[tid] * rs;
        scs[tid] = sc;
        shs[tid] = beta[tid] - sc * mu;
    }
    {
        const float4* W4 = (const float4*)W;
        float4* Wsh4 = (float4*)Wsh;
        for (int i = tid; i < 1024; i += 256) Wsh4[i] = W4[i];
    }
    int row0 = blockIdx.x * 32;
    if (tid >= 224) din[tid - 224] = dinv[row0 + tid - 224];
    __syncthreads();
    {
        const ushort2* r2 = (const ushort2*)(r + (size_t)row0 * 64);
        for (int i = tid; i < 1024; i += 256) {
            ushort2 u = r2[i];
            int base = 2 * i;
            int kk = base & 63;
            hsh[base] = fmaf(bf2f(u.x), scs[kk], shs[kk]);
            hsh[base + 1] = fmaf(bf2f(u.y), scs[kk + 1], shs[kk + 1]);
        }
    }
    __syncthreads();
    int c = tid & 63, rsl = tid >> 6;
    float acc[8];
#pragma unroll
    for (int j = 0; j < 8; ++j) acc[j] = 0.0f;
    for (int k = 0; k < 64; k += 4) {
        float w0 = Wsh[(k + 0) * 64 + c];
        float w1 = Wsh[(k + 1) * 64 + c];
        float w2 = Wsh[(k + 2) * 64 + c];
        float w3 = Wsh[(k + 3) * 64 + c];
#pragma unroll
        for (int j = 0; j < 8; ++j) {
            float4 hv = *(const float4*)&hsh[(rsl * 8 + j) * 64 + k];
            acc[j] = fmaf(hv.x, w0, fmaf(hv.y, w1, fmaf(hv.z, w2, fmaf(hv.w, w3, acc[j]))));
        }
    }
#pragma unroll
    for (int j = 0; j < 8; ++j) {
        int rr = rsl * 8 + j;
        out[(size_t)(row0 + rr) * 64 + c] = f2bf(acc[j] * din[rr]);
    }
}

// ------- gather: r = relu(dinv[d]*(u'[d] + sum w*u'[s]) + bias), bf16 in/out -------

__global__ void __launch_bounds__(256) k_gather(
        const bf16_t* __restrict__ t, const int* __restrict__ offsets,
        const int* __restrict__ ends, const int2* __restrict__ csr,
        const float* __restrict__ dinv, const float* __restrict__ bias,
        bf16_t* __restrict__ rout) {
    int wid = (blockIdx.x * 256 + threadIdx.x) >> 6;
    int lane = threadIdx.x & 63;
    if (wid >= N_NODES) return;
    float acc = bf2f(t[(size_t)wid * 64 + lane]);  // self edge, w=1
    int e0 = offsets[wid], e1 = ends[wid];
    for (int base = e0; base < e1; base += 64) {
        int n = e1 - base;
        n = (n > 64) ? 64 : n;
        int2 pe = make_int2(wid, 0);  // pad: own row, weight 0
        if (lane < n) pe = csr[base + lane];
        int ng = (n + 7) >> 3;
        for (int g = 0; g < ng; ++g) {
            int j = g * 8;
            int s[8];
            float w[8];
#pragma unroll
            for (int u = 0; u < 8; ++u) {
                s[u] = __shfl(pe.x, j + u, 64);
                w[u] = __int_as_float(__shfl(pe.y, j + u, 64));
            }
            float v[8];
#pragma unroll
            for (int u = 0; u < 8; ++u) v[u] = bf2f(t[(size_t)s[u] * 64 + lane]);
#pragma unroll
            for (int u = 0; u < 8; ++u) acc = fmaf(w[u], v[u], acc);
        }
    }
    float rv = fmaxf(fmaf(acc, dinv[wid], bias[lane]), 0.0f);
    rout[(size_t)wid * 64 + lane] = f2bf(rv);
}

// ------- BN stats of a bf16 feature array, 8-binned (grid-stride, 1024 blocks) -------

__global__ void __launch_bounds__(256) k_bnstats(const bf16_t* __restrict__ r,
                                                 float* __restrict__ statsout) {
    __shared__ float s1[256], s2[256];
    int tid = threadIdx.x;
    int c = tid & 63, rsl = tid >> 6;
    float sum = 0.0f, ssq = 0.0f;
    for (int tile = blockIdx.x; tile < NTILES; tile += gridDim.x) {
        int row0 = tile * 32;
#pragma unroll
        for (int j = 0; j < 8; ++j) {
            float v = bf2f(r[(size_t)(row0 + rsl * 8 + j) * 64 + c]);
            sum += v;
            ssq += v * v;
        }
    }
    s1[tid] = sum; s2[tid] = ssq;
    __syncthreads();
    if (tid < 64) {
        int bin = blockIdx.x & 7;
        atomicAdd(&statsout[bin * 128 + tid],
                  s1[tid] + s1[tid + 64] + s1[tid + 128] + s1[tid + 192]);
        atomicAdd(&statsout[bin * 128 + 64 + tid],
                  s2[tid] + s2[tid + 64] + s2[tid + 128] + s2[tid + 192]);
    }
}

// ------- pooling over sorted batch (run-length) + fused layer-2 BN stats -------

__global__ void __launch_bounds__(256) k_pool(const int* __restrict__ batch,
                                              const bf16_t* __restrict__ h,
                                              float* __restrict__ pooled,
                                              int* __restrict__ gcount,
                                              float* __restrict__ statsout) {
    __shared__ float s1[256], s2[256];
    int tid = threadIdx.x;
    int c = tid & 63;
    int wsub = tid >> 6;  // 0..3
    int start = blockIdx.x * POOL_ROWS;
    int end = start + POOL_ROWS; if (end > N_NODES) end = N_NODES;
    int cur = -1, cnt = 0;
    float acc = 0.0f, sum = 0.0f, ssq = 0.0f;
    for (int r = start + wsub; r < end; r += 4) {
        int g = batch[r];
        float v = bf2f(h[(size_t)r * 64 + c]);
        if (g != cur) {
            if (cur >= 0) {
                atomicAdd(&pooled[cur * 64 + c], acc);
                if (c == 0) atomicAdd(&gcount[cur], cnt);
            }
            cur = g; acc = 0.0f; cnt = 0;
        }
        acc += v; cnt += 1;
        sum += v; ssq += v * v;
    }
    if (cur >= 0) {
        atomicAdd(&pooled[cur * 64 + c], acc);
        if (c == 0) atomicAdd(&gcount[cur], cnt);
    }
    s1[tid] = sum; s2[tid] = ssq;
    __syncthreads();
    if (tid < 64) {
        int bin = blockIdx.x & 7;
        atomicAdd(&statsout[bin * 128 + tid],
                  s1[tid] + s1[tid + 64] + s1[tid + 128] + s1[tid + 192]);
        atomicAdd(&statsout[bin * 128 + 64 + tid],
                  s2[tid] + s2[tid + 64] + s2[tid + 128] + s2[tid + 192]);
    }
}

// ------- head: BN affine from binned stats folded via counts, mlp, log_softmax -------

__global__ void k_head(const float* __restrict__ pooled, const int* __restrict__ gcount,
                       const float* __restrict__ stats, const float* __restrict__ gamma,
                       const float* __restrict__ beta, const float* __restrict__ w1,
                       const float* __restrict__ b1, const float* __restrict__ w2,
                       const float* __restrict__ b2, float* __restrict__ out) {
    __shared__ float p[64];
    __shared__ float hid[64];
    __shared__ float o[2];
    int g = blockIdx.x, c = threadIdx.x;
    float s = 0.0f, q = 0.0f;
#pragma unroll
    for (int b = 0; b < 8; ++b) {
        s += stats[b * 128 + c];
        q += stats[b * 128 + 64 + c];
    }
    const float invn = 1.0f / (float)N_NODES;
    float mu = s * invn;
    float var = q * invn - mu * mu;
    float rs = rsqrtf(var + BN_EPS);
    float sc = gamma[c] * rs;
    float sh = beta[c] - sc * mu;
    p[c] = sc * pooled[g * 64 + c] + (float)gcount[g] * sh;
    __syncthreads();
    float acc = b1[c];
#pragma unroll
    for (int k = 0; k < 64; ++k) acc += p[k] * w1[k * 64 + c];
    hid[c] = fmaxf(acc, 0.0f);
    __syncthreads();
    if (c < 2) {
        float a = b2[c];
#pragma unroll
        for (int k = 0; k < 64; ++k) a += hid[k] * w2[k * 2 + c];
        o[c] = a;
    }
    __syncthreads();
    if (c == 0) {
        float m = fmaxf(o[0], o[1]);
        float l = m + logf(expf(o[0] - m) + expf(o[1] - m));
        out[g * 2 + 0] = o[0] - l;
        out[g * 2 + 1] = o[1] - l;
    }
}

extern "C" void kernel_launch(void* const* d_in, const int* in_sizes, int n_in,
                              void* d_out, int out_size, void* d_ws, size_t ws_size,
                              hipStream_t stream) {
    const float* x        = (const float*)d_in[0];
    const int*   ei       = (const int*)d_in[1];
    const int*   batch    = (const int*)d_in[2];
    const float* edge_attr= (const float*)d_in[3];
    const float* W0       = (const float*)d_in[4];
    const float* b0       = (const float*)d_in[5];
    const float* Ws       = (const float*)d_in[6];
    const float* bs       = (const float*)d_in[7];
    const float* gammas   = (const float*)d_in[8];
    const float* betas    = (const float*)d_in[9];
    const float* lin1_w   = (const float*)d_in[10];
    const float* lin1_b   = (const float*)d_in[11];
    const float* lin2_w   = (const float*)d_in[12];
    const float* lin2_b   = (const float*)d_in[13];
    float* out = (float*)d_out;

    const int* src = ei;
    const int* dst = ei + N_EDGES;

    // workspace layout (float units). csr/ebuf: NBUCK*BCAP int2 = 3,211,264 floats.
    float*  ws0      = (float*)d_ws;
    float*  dinv     = ws0;                             // [0, 100004)
    int*    offsets  = (int*)(ws0 + 100004);            // [100004, 200008)
    int*    ends     = (int*)(ws0 + 200008);            // [200008, 300012)
    int2*   csr      = (int2*)(ws0 + 300012);           // [300012, 3511276)
    bf16_t* tB       = (bf16_t*)(ws0 + 3511276);        // [3511276, 6711276)  u' rows
    bf16_t* rA       = (bf16_t*)(ws0 + 6711276);        // [6711276, 9911276)  r rows
    float*  stats    = ws0 + 9911276;                   // 3*1024
    float*  pooled   = stats + 3 * 1024;                // 16384
    int*    gcount   = (int*)(pooled + NGRAPH * 64);    // 256
    int*    bucket_cursor = (int*)(gcount + NGRAPH);    // 196
    // transient alias: ebuf spans tB and the first 11260 floats of rA
    // (dead after k_bsort; tB first written by k_mm0, rA by k_gather — both later)
    int2*  ebuf = (int2*)tB;

    const int nblk_g   = N_NODES * 64 / 256;   // 25000 (wave per node)
    const int nblk_mm  = NTILES;               // 3125

    hipMemsetAsync(stats, 0, (3 * 1024 + NGRAPH * 64 + NGRAPH) * sizeof(float), stream);

    // ---- CSR build: init cursors -> bucket fill -> in-bucket sort ----
    k_init<<<1, 256, 0, stream>>>(bucket_cursor);
    k_bfill<<<NBLK_B, 256, 0, stream>>>(src, dst, (const float2*)edge_attr,
                                        bucket_cursor, ebuf);
    k_bsort<<<NBUCK, 512, 0, stream>>>(bucket_cursor, ebuf, offsets, ends, csr, dinv);

    // ---- layer 0: mm0 (dinv∘(x@W0)) -> gather(+b0,relu) -> r0 ----
    k_mm0<<<nblk_mm, 256, 0, stream>>>(x, dinv, W0, tB);
    k_gather<<<nblk_g, 256, 0, stream>>>(tB, offsets, ends, csr, dinv, b0, rA);
    k_bnstats<<<1024, 256, 0, stream>>>(rA, stats);

    // ---- layer 1 ----
    k_affmm<<<nblk_mm, 256, 0, stream>>>(rA, dinv, stats, gammas, betas, Ws, tB);
    k_gather<<<nblk_g, 256, 0, stream>>>(tB, offsets, ends, csr, dinv, bs, rA);
    k_bnstats<<<1024, 256, 0, stream>>>(rA, stats + 1024);

    // ---- layer 2 ----
    k_affmm<<<nblk_mm, 256, 0, stream>>>(rA, dinv, stats + 1024, gammas + 64, betas + 64,
                                         Ws + 64 * 64, tB);
    k_gather<<<nblk_g, 256, 0, stream>>>(tB, offsets, ends, csr, dinv, bs + 64, rA);

    // ---- pool (+ fused layer-2 stats) + head ----
    k_pool<<<(N_NODES + POOL_ROWS - 1) / POOL_ROWS, 256, 0, stream>>>(
        batch, rA, pooled, gcount, stats + 2048);
    k_head<<<NGRAPH, 64, 0, stream>>>(pooled, gcount, stats + 2048,
                                      gammas + 2 * 64, betas + 2 * 64,
                                      lin1_w, lin1_b, lin2_w, lin2_b, out);
}

// Round 16
// 343.999 us; speedup vs baseline: 2.0002x; 1.0541x over previous
//
#include <hip/hip_runtime.h>
#include <math.h>

#define N_NODES 100000
#define N_EDGES 1250000
#define NGRAPH 256
#define IN_DIM 8
#define DIM 64
#define BN_EPS 1e-5f

#define BSHIFT 9
#define BNODES 512
#define NBUCK 196           // ceil(100000 / 512)
#define BCAP 8192           // fixed bucket capacity (mean 6400, +22 sigma)
#define NBLK_B 512
#define CHUNK 2442          // ceil(1250000 / 512)
#define POOL_ROWS 128
#define NTILES 3125         // N_NODES / 32

typedef unsigned short bf16_t;

static __device__ inline float bf2f(bf16_t u) {
    return __uint_as_float(((unsigned int)u) << 16);
}
static __device__ inline bf16_t f2bf(float f) {
    unsigned int b = __float_as_uint(f);
    b += 0x7fffu + ((b >> 16) & 1u);
    return (bf16_t)(b >> 16);
}

// ------- bucket fill: per-block LDS count -> chunk reservation -> burst writes -------
// bucket_cursor[] is zero-initialized by the big memset; fixed base = b*BCAP.

__global__ void __launch_bounds__(256) k_bfill(const int* __restrict__ src,
                                               const int* __restrict__ dst,
                                               const float2* __restrict__ edge_attr,
                                               int* __restrict__ bucket_cursor,
                                               int2* __restrict__ ebuf) {
    __shared__ int lh[NBUCK], lbase[NBUCK];
    int tid = threadIdx.x;
    if (tid < NBUCK) lh[tid] = 0;
    __syncthreads();
    int e0 = blockIdx.x * CHUNK;
    int e1 = e0 + CHUNK; if (e1 > N_EDGES) e1 = N_EDGES;
    for (int e = e0 + tid; e < e1; e += 256)
        atomicAdd(&lh[dst[e] >> BSHIFT], 1);
    __syncthreads();
    if (tid < NBUCK) {
        lbase[tid] = tid * BCAP + atomicAdd(&bucket_cursor[tid], lh[tid]);
        lh[tid] = 0;
    }
    __syncthreads();
    for (int e = e0 + tid; e < e1; e += 256) {
        int d = dst[e];
        int b = d >> BSHIFT;
        int pos = lbase[b] + atomicAdd(&lh[b], 1);
        int pk = src[e] | ((d & (BNODES - 1)) << 17);  // src<2^17, dlocal<2^9
        ebuf[pos] = make_int2(pk, __float_as_int(edge_attr[e].y));
    }
}

// ------- bucket sort: CSR placement (raw w) + offsets/ends + dinv, LDS-local -------

__global__ void __launch_bounds__(512) k_bsort(
        const int* __restrict__ bucket_cursor, const int2* __restrict__ ebuf,
        int* __restrict__ offsets, int* __restrict__ ends, int2* __restrict__ csr,
        float* __restrict__ dinv) {
    __shared__ int cnt[BNODES];
    __shared__ float wsum[BNODES];
    __shared__ int tsum[BNODES];
    int tid = threadIdx.x;
    int b = blockIdx.x;
    int nbase = b * BNODES;
    int nloc = N_NODES - nbase; if (nloc > BNODES) nloc = BNODES;
    cnt[tid] = 0; wsum[tid] = 0.0f;
    __syncthreads();
    int e0 = b * BCAP;
    int ecnt = bucket_cursor[b];
    for (int e = e0 + tid; e < e0 + ecnt; e += 512) {
        int2 p = ebuf[e];
        int dl = p.x >> 17;
        atomicAdd(&cnt[dl], 1);
        atomicAdd(&wsum[dl], __int_as_float(p.y));
    }
    __syncthreads();
    int myc = cnt[tid];
    tsum[tid] = myc;
    __syncthreads();
    for (int off = 1; off < 512; off <<= 1) {
        int add = (tid >= off) ? tsum[tid - off] : 0;
        __syncthreads();
        tsum[tid] += add;
        __syncthreads();
    }
    int excl = tsum[tid] - myc;
    if (tid < nloc) {
        offsets[nbase + tid] = e0 + excl;
        ends[nbase + tid] = e0 + excl + myc;
        dinv[nbase + tid] = rsqrtf(wsum[tid] + 1.0f);  // +1 = self-loop weight
    }
    cnt[tid] = excl;  // cursor
    __syncthreads();
    for (int e = e0 + tid; e < e0 + ecnt; e += 512) {
        int2 p = ebuf[e];
        int dl = p.x >> 17;
        int pos = e0 + atomicAdd(&cnt[dl], 1);
        csr[pos] = make_int2(p.x & 0x1FFFF, p.y);  // (src, raw w)
    }
}

// ------- fused layer 0: 8-ch weighted-x aggregation + 8x64 matvec + relu -------
// r0[d] = relu( dinv[d] * ( (dinv[d]x[d] + sum_e w*dinv[s]*x[s]) @ W0 ) + b0 )
// one wave per node; lane = (slot u = lane>>3, channel k = lane&7).
// 64-edge window: coalesced CSR load; 8 groups x (x-row + dinv) loads in flight.

__global__ void __launch_bounds__(256) k_gather0x(
        const float* __restrict__ x, const int* __restrict__ offsets,
        const int* __restrict__ ends, const int2* __restrict__ csr,
        const float* __restrict__ dinv, const float* __restrict__ W0,
        const float* __restrict__ b0, bf16_t* __restrict__ rout) {
    __shared__ float Wsh[IN_DIM * 64];
    __shared__ float bsh[64];
    int tid = threadIdx.x;
    for (int i = tid; i < IN_DIM * 64; i += 256) Wsh[i] = W0[i];
    if (tid < 64) bsh[tid] = b0[tid];
    __syncthreads();
    int wid = (blockIdx.x * 256 + tid) >> 6;
    int lane = tid & 63;
    if (wid >= N_NODES) return;
    int k = lane & 7;      // channel
    int u = lane >> 3;     // edge slot
    float dvd = dinv[wid];
    float acc = (u == 0) ? dvd * x[wid * 8 + k] : 0.0f;  // self term (w=1)
    int e0 = offsets[wid], e1 = ends[wid];
    for (int base = e0; base < e1; base += 64) {
        int n = e1 - base;
        n = (n > 64) ? 64 : n;
        int2 pe = make_int2(wid, 0);  // pad: w=0
        if (lane < n) pe = csr[base + lane];
        int ng = (n + 7) >> 3;
        if (ng == 8) {
            int s[8]; float w[8], v[8], dv[8];
#pragma unroll
            for (int g = 0; g < 8; ++g) {
                s[g] = __shfl(pe.x, g * 8 + u, 64);
                w[g] = __int_as_float(__shfl(pe.y, g * 8 + u, 64));
            }
#pragma unroll
            for (int g = 0; g < 8; ++g) { v[g] = x[s[g] * 8 + k]; dv[g] = dinv[s[g]]; }
#pragma unroll
            for (int g = 0; g < 8; ++g) acc = fmaf(w[g] * dv[g], v[g], acc);
        } else {
            for (int g = 0; g < ng; ++g) {
                int s = __shfl(pe.x, g * 8 + u, 64);
                float w = __int_as_float(__shfl(pe.y, g * 8 + u, 64));
                acc = fmaf(w * dinv[s], x[s * 8 + k], acc);
            }
        }
    }
    // reduce across the 8 edge slots (lane bits 3..5)
    acc += __shfl_xor(acc, 8, 64);
    acc += __shfl_xor(acc, 16, 64);
    acc += __shfl_xor(acc, 32, 64);
    // broadcast agg[0..7] within each 8-lane sub-group
    float a[8];
#pragma unroll
    for (int kk = 0; kk < 8; ++kk) a[kk] = __shfl(acc, kk, 8);
    // matvec: output channel c = lane
    float t = 0.0f;
#pragma unroll
    for (int kk = 0; kk < 8; ++kk) t = fmaf(a[kk], Wsh[kk * 64 + lane], t);
    float rv = fmaxf(fmaf(t, dvd, bsh[lane]), 0.0f);
    rout[(size_t)wid * 64 + lane] = f2bf(rv);
}

// ------- affmm: u' = dinv ∘ (affine(r) @ W), bf16 in/out (32 rows/block) -------

__global__ void __launch_bounds__(256) k_affmm(
        const bf16_t* __restrict__ r, const float* __restrict__ dinv,
        const float* __restrict__ statsin, const float* __restrict__ gamma,
        const float* __restrict__ beta, const float* __restrict__ W,
        bf16_t* __restrict__ out) {
    __shared__ float Wsh[64 * 64];
    __shared__ float hsh[32 * 64];
    __shared__ float scs[64], shs[64];
    __shared__ float din[32];
    int tid = threadIdx.x;
    if (tid < 64) {
        float s = 0.0f, q = 0.0f;
#pragma unroll
        for (int b = 0; b < 8; ++b) {
            s += statsin[b * 128 + tid];
            q += statsin[b * 128 + 64 + tid];
        }
        const float invn = 1.0f / (float)N_NODES;
        float mu = s * invn;
        float var = q * invn - mu * mu;
        float rs = rsqrtf(var + BN_EPS);
        float sc = gamma[tid] * rs;
        scs[tid] = sc;
        shs[tid] = beta[tid] - sc * mu;
    }
    {
        const float4* W4 = (const float4*)W;
        float4* Wsh4 = (float4*)Wsh;
        for (int i = tid; i < 1024; i += 256) Wsh4[i] = W4[i];
    }
    int row0 = blockIdx.x * 32;
    if (tid >= 224) din[tid - 224] = dinv[row0 + tid - 224];
    __syncthreads();
    {
        const ushort2* r2 = (const ushort2*)(r + (size_t)row0 * 64);
        for (int i = tid; i < 1024; i += 256) {
            ushort2 u = r2[i];
            int base = 2 * i;
            int kk = base & 63;
            hsh[base] = fmaf(bf2f(u.x), scs[kk], shs[kk]);
            hsh[base + 1] = fmaf(bf2f(u.y), scs[kk + 1], shs[kk + 1]);
        }
    }
    __syncthreads();
    int c = tid & 63, rsl = tid >> 6;
    float acc[8];
#pragma unroll
    for (int j = 0; j < 8; ++j) acc[j] = 0.0f;
    for (int k = 0; k < 64; k += 4) {
        float w0 = Wsh[(k + 0) * 64 + c];
        float w1 = Wsh[(k + 1) * 64 + c];
        float w2 = Wsh[(k + 2) * 64 + c];
        float w3 = Wsh[(k + 3) * 64 + c];
#pragma unroll
        for (int j = 0; j < 8; ++j) {
            float4 hv = *(const float4*)&hsh[(rsl * 8 + j) * 64 + k];
            acc[j] = fmaf(hv.x, w0, fmaf(hv.y, w1, fmaf(hv.z, w2, fmaf(hv.w, w3, acc[j]))));
        }
    }
#pragma unroll
    for (int j = 0; j < 8; ++j) {
        int rr = rsl * 8 + j;
        out[(size_t)(row0 + rr) * 64 + c] = f2bf(acc[j] * din[rr]);
    }
}

// ------- gather: r = relu(dinv[d]*(u'[d] + sum w*u'[s]) + bias), bf16 in/out -------

__global__ void __launch_bounds__(256) k_gather(
        const bf16_t* __restrict__ t, const int* __restrict__ offsets,
        const int* __restrict__ ends, const int2* __restrict__ csr,
        const float* __restrict__ dinv, const float* __restrict__ bias,
        bf16_t* __restrict__ rout) {
    int wid = (blockIdx.x * 256 + threadIdx.x) >> 6;
    int lane = threadIdx.x & 63;
    if (wid >= N_NODES) return;
    float acc = bf2f(t[(size_t)wid * 64 + lane]);  // self edge, w=1
    int e0 = offsets[wid], e1 = ends[wid];
    for (int base = e0; base < e1; base += 64) {
        int n = e1 - base;
        n = (n > 64) ? 64 : n;
        int2 pe = make_int2(wid, 0);  // pad: own row, weight 0
        if (lane < n) pe = csr[base + lane];
        int ng = (n + 7) >> 3;
        for (int g = 0; g < ng; ++g) {
            int j = g * 8;
            int s[8];
            float w[8];
#pragma unroll
            for (int u = 0; u < 8; ++u) {
                s[u] = __shfl(pe.x, j + u, 64);
                w[u] = __int_as_float(__shfl(pe.y, j + u, 64));
            }
            float v[8];
#pragma unroll
            for (int u = 0; u < 8; ++u) v[u] = bf2f(t[(size_t)s[u] * 64 + lane]);
#pragma unroll
            for (int u = 0; u < 8; ++u) acc = fmaf(w[u], v[u], acc);
        }
    }
    float rv = fmaxf(fmaf(acc, dinv[wid], bias[lane]), 0.0f);
    rout[(size_t)wid * 64 + lane] = f2bf(rv);
}

// ------- BN stats of a bf16 feature array, 8-binned (grid-stride, 1024 blocks) -------

__global__ void __launch_bounds__(256) k_bnstats(const bf16_t* __restrict__ r,
                                                 float* __restrict__ statsout) {
    __shared__ float s1[256], s2[256];
    int tid = threadIdx.x;
    int c = tid & 63, rsl = tid >> 6;
    float sum = 0.0f, ssq = 0.0f;
    for (int tile = blockIdx.x; tile < NTILES; tile += gridDim.x) {
        int row0 = tile * 32;
#pragma unroll
        for (int j = 0; j < 8; ++j) {
            float v = bf2f(r[(size_t)(row0 + rsl * 8 + j) * 64 + c]);
            sum += v;
            ssq += v * v;
        }
    }
    s1[tid] = sum; s2[tid] = ssq;
    __syncthreads();
    if (tid < 64) {
        int bin = blockIdx.x & 7;
        atomicAdd(&statsout[bin * 128 + tid],
                  s1[tid] + s1[tid + 64] + s1[tid + 128] + s1[tid + 192]);
        atomicAdd(&statsout[bin * 128 + 64 + tid],
                  s2[tid] + s2[tid + 64] + s2[tid + 128] + s2[tid + 192]);
    }
}

// ------- pooling over sorted batch (run-length) + fused layer-2 BN stats -------

__global__ void __launch_bounds__(256) k_pool(const int* __restrict__ batch,
                                              const bf16_t* __restrict__ h,
                                              float* __restrict__ pooled,
                                              int* __restrict__ gcount,
                                              float* __restrict__ statsout) {
    __shared__ float s1[256], s2[256];
    int tid = threadIdx.x;
    int c = tid & 63;
    int wsub = tid >> 6;  // 0..3
    int start = blockIdx.x * POOL_ROWS;
    int end = start + POOL_ROWS; if (end > N_NODES) end = N_NODES;
    int cur = -1, cnt = 0;
    float acc = 0.0f, sum = 0.0f, ssq = 0.0f;
    for (int r = start + wsub; r < end; r += 4) {
        int g = batch[r];
        float v = bf2f(h[(size_t)r * 64 + c]);
        if (g != cur) {
            if (cur >= 0) {
                atomicAdd(&pooled[cur * 64 + c], acc);
                if (c == 0) atomicAdd(&gcount[cur], cnt);
            }
            cur = g; acc = 0.0f; cnt = 0;
        }
        acc += v; cnt += 1;
        sum += v; ssq += v * v;
    }
    if (cur >= 0) {
        atomicAdd(&pooled[cur * 64 + c], acc);
        if (c == 0) atomicAdd(&gcount[cur], cnt);
    }
    s1[tid] = sum; s2[tid] = ssq;
    __syncthreads();
    if (tid < 64) {
        int bin = blockIdx.x & 7;
        atomicAdd(&statsout[bin * 128 + tid],
                  s1[tid] + s1[tid + 64] + s1[tid + 128] + s1[tid + 192]);
        atomicAdd(&statsout[bin * 128 + 64 + tid],
                  s2[tid] + s2[tid + 64] + s2[tid + 128] + s2[tid + 192]);
    }
}

// ------- head: BN affine from binned stats folded via counts, mlp, log_softmax -------

__global__ void k_head(const float* __restrict__ pooled, const int* __restrict__ gcount,
                       const float* __restrict__ stats, const float* __restrict__ gamma,
                       const float* __restrict__ beta, const float* __restrict__ w1,
                       const float* __restrict__ b1, const float* __restrict__ w2,
                       const float* __restrict__ b2, float* __restrict__ out) {
    __shared__ float p[64];
    __shared__ float hid[64];
    __shared__ float o[2];
    int g = blockIdx.x, c = threadIdx.x;
    float s = 0.0f, q = 0.0f;
#pragma unroll
    for (int b = 0; b < 8; ++b) {
        s += stats[b * 128 + c];
        q += stats[b * 128 + 64 + c];
    }
    const float invn = 1.0f / (float)N_NODES;
    float mu = s * invn;
    float var = q * invn - mu * mu;
    float rs = rsqrtf(var + BN_EPS);
    float sc = gamma[c] * rs;
    float sh = beta[c] - sc * mu;
    p[c] = sc * pooled[g * 64 + c] + (float)gcount[g] * sh;
    __syncthreads();
    float acc = b1[c];
#pragma unroll
    for (int k = 0; k < 64; ++k) acc += p[k] * w1[k * 64 + c];
    hid[c] = fmaxf(acc, 0.0f);
    __syncthreads();
    if (c < 2) {
        float a = b2[c];
#pragma unroll
        for (int k = 0; k < 64; ++k) a += hid[k] * w2[k * 2 + c];
        o[c] = a;
    }
    __syncthreads();
    if (c == 0) {
        float m = fmaxf(o[0], o[1]);
        float l = m + logf(expf(o[0] - m) + expf(o[1] - m));
        out[g * 2 + 0] = o[0] - l;
        out[g * 2 + 1] = o[1] - l;
    }
}

extern "C" void kernel_launch(void* const* d_in, const int* in_sizes, int n_in,
                              void* d_out, int out_size, void* d_ws, size_t ws_size,
                              hipStream_t stream) {
    const float* x        = (const float*)d_in[0];
    const int*   ei       = (const int*)d_in[1];
    const int*   batch    = (const int*)d_in[2];
    const float* edge_attr= (const float*)d_in[3];
    const float* W0       = (const float*)d_in[4];
    const float* b0       = (const float*)d_in[5];
    const float* Ws       = (const float*)d_in[6];
    const float* bs       = (const float*)d_in[7];
    const float* gammas   = (const float*)d_in[8];
    const float* betas    = (const float*)d_in[9];
    const float* lin1_w   = (const float*)d_in[10];
    const float* lin1_b   = (const float*)d_in[11];
    const float* lin2_w   = (const float*)d_in[12];
    const float* lin2_b   = (const float*)d_in[13];
    float* out = (float*)d_out;

    const int* src = ei;
    const int* dst = ei + N_EDGES;

    // workspace layout (float units). csr/ebuf: NBUCK*BCAP int2 = 3,211,264 floats.
    float*  ws0      = (float*)d_ws;
    float*  dinv     = ws0;                             // [0, 100004)
    int*    offsets  = (int*)(ws0 + 100004);            // [100004, 200008)
    int*    ends     = (int*)(ws0 + 200008);            // [200008, 300012)
    int2*   csr      = (int2*)(ws0 + 300012);           // [300012, 3511276)
    bf16_t* tB       = (bf16_t*)(ws0 + 3511276);        // [3511276, 6711276)  u' rows
    bf16_t* rA       = (bf16_t*)(ws0 + 6711276);        // [6711276, 9911276)  r rows
    float*  stats    = ws0 + 9911276;                   // 3*1024
    float*  pooled   = stats + 3 * 1024;                // 16384
    int*    gcount   = (int*)(pooled + NGRAPH * 64);    // 256
    int*    bucket_cursor = (int*)(gcount + NGRAPH);    // 196 (zero-init by memset)
    // transient alias: ebuf spans tB and the start of rA (dead after k_bsort;
    // tB first written by layer-1 affmm, rA by gather0x — both after bsort)
    int2*  ebuf = (int2*)tB;

    const int nblk_g   = N_NODES * 64 / 256;   // 25000 (wave per node)
    const int nblk_mm  = NTILES;               // 3125

    // one memset: stats + pooled + gcount + bucket_cursor (contiguous)
    hipMemsetAsync(stats, 0, (3 * 1024 + NGRAPH * 64 + NGRAPH + NBUCK) * sizeof(float),
                   stream);

    // ---- CSR build: bucket fill -> in-bucket sort ----
    k_bfill<<<NBLK_B, 256, 0, stream>>>(src, dst, (const float2*)edge_attr,
                                        bucket_cursor, ebuf);
    k_bsort<<<NBUCK, 512, 0, stream>>>(bucket_cursor, ebuf, offsets, ends, csr, dinv);

    // ---- layer 0: fused x-space aggregation + 8x64 matvec -> r0 ----
    k_gather0x<<<nblk_g, 256, 0, stream>>>(x, offsets, ends, csr, dinv, W0, b0, rA);
    k_bnstats<<<1024, 256, 0, stream>>>(rA, stats);

    // ---- layer 1 ----
    k_affmm<<<nblk_mm, 256, 0, stream>>>(rA, dinv, stats, gammas, betas, Ws, tB);
    k_gather<<<nblk_g, 256, 0, stream>>>(tB, offsets, ends, csr, dinv, bs, rA);
    k_bnstats<<<1024, 256, 0, stream>>>(rA, stats + 1024);

    // ---- layer 2 ----
    k_affmm<<<nblk_mm, 256, 0, stream>>>(rA, dinv, stats + 1024, gammas + 64, betas + 64,
                                         Ws + 64 * 64, tB);
    k_gather<<<nblk_g, 256, 0, stream>>>(tB, offsets, ends, csr, dinv, bs + 64, rA);

    // ---- pool (+ fused layer-2 stats) + head ----
    k_pool<<<(N_NODES + POOL_ROWS - 1) / POOL_ROWS, 256, 0, stream>>>(
        batch, rA, pooled, gcount, stats + 2048);
    k_head<<<NGRAPH, 64, 0, stream>>>(pooled, gcount, stats + 2048,
                                      gammas + 2 * 64, betas + 2 * 64,
                                      lin1_w, lin1_b, lin2_w, lin2_b, out);
}

// Round 17
// 343.737 us; speedup vs baseline: 2.0017x; 1.0008x over previous
//
#include <hip/hip_runtime.h>
#include <math.h>

#define N_NODES 100000
#define N_EDGES 1250000
#define NGRAPH 256
#define IN_DIM 8
#define DIM 64
#define BN_EPS 1e-5f

#define BSHIFT 9
#define BNODES 512
#define NBUCK 196           // ceil(100000 / 512)
#define BCAP 8192           // fixed bucket capacity (mean 6400, +22 sigma)
#define NBLK_B 256
#define CHUNK 4883          // ceil(1250000 / 256)
#define POOL_ROWS 128
#define NTILES 3125         // N_NODES / 32

typedef unsigned short bf16_t;

static __device__ inline float bf2f(bf16_t u) {
    return __uint_as_float(((unsigned int)u) << 16);
}
static __device__ inline bf16_t f2bf(float f) {
    unsigned int b = __float_as_uint(f);
    b += 0x7fffu + ((b >> 16) & 1u);
    return (bf16_t)(b >> 16);
}

// ------- bucket fill: per-block LDS count -> chunk reservation -> burst writes -------
// bucket_cursor[] is zero-initialized by the big memset; fixed base = b*BCAP.

__global__ void __launch_bounds__(256) k_bfill(const int* __restrict__ src,
                                               const int* __restrict__ dst,
                                               const float2* __restrict__ edge_attr,
                                               int* __restrict__ bucket_cursor,
                                               int2* __restrict__ ebuf) {
    __shared__ int lh[NBUCK], lbase[NBUCK];
    int tid = threadIdx.x;
    if (tid < NBUCK) lh[tid] = 0;
    __syncthreads();
    int e0 = blockIdx.x * CHUNK;
    int e1 = e0 + CHUNK; if (e1 > N_EDGES) e1 = N_EDGES;
    for (int e = e0 + tid; e < e1; e += 256)
        atomicAdd(&lh[dst[e] >> BSHIFT], 1);
    __syncthreads();
    if (tid < NBUCK) {
        lbase[tid] = tid * BCAP + atomicAdd(&bucket_cursor[tid], lh[tid]);
        lh[tid] = 0;
    }
    __syncthreads();
    for (int e = e0 + tid; e < e1; e += 256) {
        int d = dst[e];
        int b = d >> BSHIFT;
        int pos = lbase[b] + atomicAdd(&lh[b], 1);
        int pk = src[e] | ((d & (BNODES - 1)) << 17);  // src<2^17, dlocal<2^9
        ebuf[pos] = make_int2(pk, __float_as_int(edge_attr[e].y));
    }
}

// ------- bucket sort: CSR placement (raw w) + offsets/ends + dinv, LDS-local -------

__global__ void __launch_bounds__(512) k_bsort(
        const int* __restrict__ bucket_cursor, const int2* __restrict__ ebuf,
        int* __restrict__ offsets, int* __restrict__ ends, int2* __restrict__ csr,
        float* __restrict__ dinv) {
    __shared__ int cnt[BNODES];
    __shared__ float wsum[BNODES];
    __shared__ int tsum[BNODES];
    int tid = threadIdx.x;
    int b = blockIdx.x;
    int nbase = b * BNODES;
    int nloc = N_NODES - nbase; if (nloc > BNODES) nloc = BNODES;
    cnt[tid] = 0; wsum[tid] = 0.0f;
    __syncthreads();
    int e0 = b * BCAP;
    int ecnt = bucket_cursor[b];
    for (int e = e0 + tid; e < e0 + ecnt; e += 512) {
        int2 p = ebuf[e];
        int dl = p.x >> 17;
        atomicAdd(&cnt[dl], 1);
        atomicAdd(&wsum[dl], __int_as_float(p.y));
    }
    __syncthreads();
    int myc = cnt[tid];
    tsum[tid] = myc;
    __syncthreads();
    for (int off = 1; off < 512; off <<= 1) {
        int add = (tid >= off) ? tsum[tid - off] : 0;
        __syncthreads();
        tsum[tid] += add;
        __syncthreads();
    }
    int excl = tsum[tid] - myc;
    if (tid < nloc) {
        offsets[nbase + tid] = e0 + excl;
        ends[nbase + tid] = e0 + excl + myc;
        dinv[nbase + tid] = rsqrtf(wsum[tid] + 1.0f);  // +1 = self-loop weight
    }
    cnt[tid] = excl;  // cursor
    __syncthreads();
    for (int e = e0 + tid; e < e0 + ecnt; e += 512) {
        int2 p = ebuf[e];
        int dl = p.x >> 17;
        int pos = e0 + atomicAdd(&cnt[dl], 1);
        csr[pos] = make_int2(p.x & 0x1FFFF, p.y);  // (src, raw w)
    }
}

// ------- xscale: xs = dinv ∘ x (row-scalar), fp32, coalesced -------

__global__ void __launch_bounds__(256) k_xscale(const float* __restrict__ x,
                                                const float* __restrict__ dinv,
                                                float* __restrict__ xs) {
    int i = blockIdx.x * 256 + threadIdx.x;  // over N*8 elements
    if (i < N_NODES * 8) xs[i] = x[i] * dinv[i >> 3];
}

// ------- fused layer 0: 8-ch weighted-xs aggregation + 8x64 matvec + relu -------
// r0[d] = relu( dinv[d] * ( (xs[d] + sum_e w*xs[s]) @ W0 ) + b0 )
// one wave per node; lane = (slot u = lane>>3, channel k = lane&7).

__global__ void __launch_bounds__(256) k_gather0x(
        const float* __restrict__ xs, const int* __restrict__ offsets,
        const int* __restrict__ ends, const int2* __restrict__ csr,
        const float* __restrict__ dinv, const float* __restrict__ W0,
        const float* __restrict__ b0, bf16_t* __restrict__ rout) {
    __shared__ float Wsh[IN_DIM * 64];
    __shared__ float bsh[64];
    int tid = threadIdx.x;
    for (int i = tid; i < IN_DIM * 64; i += 256) Wsh[i] = W0[i];
    if (tid < 64) bsh[tid] = b0[tid];
    __syncthreads();
    int wid = (blockIdx.x * 256 + tid) >> 6;
    int lane = tid & 63;
    if (wid >= N_NODES) return;
    int k = lane & 7;      // channel
    int u = lane >> 3;     // edge slot
    float acc = (u == 0) ? xs[wid * 8 + k] : 0.0f;  // self term (w=1, pre-scaled)
    int e0 = offsets[wid], e1 = ends[wid];
    for (int base = e0; base < e1; base += 64) {
        int n = e1 - base;
        n = (n > 64) ? 64 : n;
        int2 pe = make_int2(wid, 0);  // pad: w=0
        if (lane < n) pe = csr[base + lane];
        int ng = (n + 7) >> 3;
        if (ng == 8) {
            int s[8]; float w[8], v[8];
#pragma unroll
            for (int g = 0; g < 8; ++g) {
                s[g] = __shfl(pe.x, g * 8 + u, 64);
                w[g] = __int_as_float(__shfl(pe.y, g * 8 + u, 64));
            }
#pragma unroll
            for (int g = 0; g < 8; ++g) v[g] = xs[s[g] * 8 + k];
#pragma unroll
            for (int g = 0; g < 8; ++g) acc = fmaf(w[g], v[g], acc);
        } else {
            for (int g = 0; g < ng; ++g) {
                int s = __shfl(pe.x, g * 8 + u, 64);
                float w = __int_as_float(__shfl(pe.y, g * 8 + u, 64));
                acc = fmaf(w, xs[s * 8 + k], acc);
            }
        }
    }
    // reduce across the 8 edge slots (lane bits 3..5)
    acc += __shfl_xor(acc, 8, 64);
    acc += __shfl_xor(acc, 16, 64);
    acc += __shfl_xor(acc, 32, 64);
    // broadcast agg[0..7] within each 8-lane sub-group
    float a[8];
#pragma unroll
    for (int kk = 0; kk < 8; ++kk) a[kk] = __shfl(acc, kk, 8);
    // matvec: output channel c = lane
    float t = 0.0f;
#pragma unroll
    for (int kk = 0; kk < 8; ++kk) t = fmaf(a[kk], Wsh[kk * 64 + lane], t);
    float rv = fmaxf(fmaf(t, dinv[wid], bsh[lane]), 0.0f);
    rout[(size_t)wid * 64 + lane] = f2bf(rv);
}

// ------- affmm: u' = dinv ∘ (affine(r) @ W), bf16 in/out (32 rows/block) -------

__global__ void __launch_bounds__(256) k_affmm(
        const bf16_t* __restrict__ r, const float* __restrict__ dinv,
        const float* __restrict__ statsin, const float* __restrict__ gamma,
        const float* __restrict__ beta, const float* __restrict__ W,
        bf16_t* __restrict__ out) {
    __shared__ float Wsh[64 * 64];
    __shared__ float hsh[32 * 64];
    __shared__ float scs[64], shs[64];
    __shared__ float din[32];
    int tid = threadIdx.x;
    if (tid < 64) {
        float s = 0.0f, q = 0.0f;
#pragma unroll
        for (int b = 0; b < 8; ++b) {
            s += statsin[b * 128 + tid];
            q += statsin[b * 128 + 64 + tid];
        }
        const float invn = 1.0f / (float)N_NODES;
        float mu = s * invn;
        float var = q * invn - mu * mu;
        float rs = rsqrtf(var + BN_EPS);
        float sc = gamma[tid] * rs;
        scs[tid] = sc;
        shs[tid] = beta[tid] - sc * mu;
    }
    {
        const float4* W4 = (const float4*)W;
        float4* Wsh4 = (float4*)Wsh;
        for (int i = tid; i < 1024; i += 256) Wsh4[i] = W4[i];
    }
    int row0 = blockIdx.x * 32;
    if (tid >= 224) din[tid - 224] = dinv[row0 + tid - 224];
    __syncthreads();
    {
        const ushort2* r2 = (const ushort2*)(r + (size_t)row0 * 64);
        for (int i = tid; i < 1024; i += 256) {
            ushort2 u = r2[i];
            int base = 2 * i;
            int kk = base & 63;
            hsh[base] = fmaf(bf2f(u.x), scs[kk], shs[kk]);
            hsh[base + 1] = fmaf(bf2f(u.y), scs[kk + 1], shs[kk + 1]);
        }
    }
    __syncthreads();
    int c = tid & 63, rsl = tid >> 6;
    float acc[8];
#pragma unroll
    for (int j = 0; j < 8; ++j) acc[j] = 0.0f;
    for (int k = 0; k < 64; k += 4) {
        float w0 = Wsh[(k + 0) * 64 + c];
        float w1 = Wsh[(k + 1) * 64 + c];
        float w2 = Wsh[(k + 2) * 64 + c];
        float w3 = Wsh[(k + 3) * 64 + c];
#pragma unroll
        for (int j = 0; j < 8; ++j) {
            float4 hv = *(const float4*)&hsh[(rsl * 8 + j) * 64 + k];
            acc[j] = fmaf(hv.x, w0, fmaf(hv.y, w1, fmaf(hv.z, w2, fmaf(hv.w, w3, acc[j]))));
        }
    }
#pragma unroll
    for (int j = 0; j < 8; ++j) {
        int rr = rsl * 8 + j;
        out[(size_t)(row0 + rr) * 64 + c] = f2bf(acc[j] * din[rr]);
    }
}

// ------- gather: r = relu(dinv[d]*(u'[d] + sum w*u'[s]) + bias), bf16 in/out -------

__global__ void __launch_bounds__(256) k_gather(
        const bf16_t* __restrict__ t, const int* __restrict__ offsets,
        const int* __restrict__ ends, const int2* __restrict__ csr,
        const float* __restrict__ dinv, const float* __restrict__ bias,
        bf16_t* __restrict__ rout) {
    int wid = (blockIdx.x * 256 + threadIdx.x) >> 6;
    int lane = threadIdx.x & 63;
    if (wid >= N_NODES) return;
    float acc = bf2f(t[(size_t)wid * 64 + lane]);  // self edge, w=1
    int e0 = offsets[wid], e1 = ends[wid];
    for (int base = e0; base < e1; base += 64) {
        int n = e1 - base;
        n = (n > 64) ? 64 : n;
        int2 pe = make_int2(wid, 0);  // pad: own row, weight 0
        if (lane < n) pe = csr[base + lane];
        int ng = (n + 7) >> 3;
        for (int g = 0; g < ng; ++g) {
            int j = g * 8;
            int s[8];
            float w[8];
#pragma unroll
            for (int u = 0; u < 8; ++u) {
                s[u] = __shfl(pe.x, j + u, 64);
                w[u] = __int_as_float(__shfl(pe.y, j + u, 64));
            }
            float v[8];
#pragma unroll
            for (int u = 0; u < 8; ++u) v[u] = bf2f(t[(size_t)s[u] * 64 + lane]);
#pragma unroll
            for (int u = 0; u < 8; ++u) acc = fmaf(w[u], v[u], acc);
        }
    }
    float rv = fmaxf(fmaf(acc, dinv[wid], bias[lane]), 0.0f);
    rout[(size_t)wid * 64 + lane] = f2bf(rv);
}

// ------- BN stats of a bf16 feature array, 8-binned (grid-stride, 1024 blocks) -------

__global__ void __launch_bounds__(256) k_bnstats(const bf16_t* __restrict__ r,
                                                 float* __restrict__ statsout) {
    __shared__ float s1[256], s2[256];
    int tid = threadIdx.x;
    int c = tid & 63, rsl = tid >> 6;
    float sum = 0.0f, ssq = 0.0f;
    for (int tile = blockIdx.x; tile < NTILES; tile += gridDim.x) {
        int row0 = tile * 32;
#pragma unroll
        for (int j = 0; j < 8; ++j) {
            float v = bf2f(r[(size_t)(row0 + rsl * 8 + j) * 64 + c]);
            sum += v;
            ssq += v * v;
        }
    }
    s1[tid] = sum; s2[tid] = ssq;
    __syncthreads();
    if (tid < 64) {
        int bin = blockIdx.x & 7;
        atomicAdd(&statsout[bin * 128 + tid],
                  s1[tid] + s1[tid + 64] + s1[tid + 128] + s1[tid + 192]);
        atomicAdd(&statsout[bin * 128 + 64 + tid],
                  s2[tid] + s2[tid + 64] + s2[tid + 128] + s2[tid + 192]);
    }
}

// ------- pooling over sorted batch (run-length) + fused layer-2 BN stats -------

__global__ void __launch_bounds__(256) k_pool(const int* __restrict__ batch,
                                              const bf16_t* __restrict__ h,
                                              float* __restrict__ pooled,
                                              int* __restrict__ gcount,
                                              float* __restrict__ statsout) {
    __shared__ float s1[256], s2[256];
    int tid = threadIdx.x;
    int c = tid & 63;
    int wsub = tid >> 6;  // 0..3
    int start = blockIdx.x * POOL_ROWS;
    int end = start + POOL_ROWS; if (end > N_NODES) end = N_NODES;
    int cur = -1, cnt = 0;
    float acc = 0.0f, sum = 0.0f, ssq = 0.0f;
    for (int r = start + wsub; r < end; r += 4) {
        int g = batch[r];
        float v = bf2f(h[(size_t)r * 64 + c]);
        if (g != cur) {
            if (cur >= 0) {
                atomicAdd(&pooled[cur * 64 + c], acc);
                if (c == 0) atomicAdd(&gcount[cur], cnt);
            }
            cur = g; acc = 0.0f; cnt = 0;
        }
        acc += v; cnt += 1;
        sum += v; ssq += v * v;
    }
    if (cur >= 0) {
        atomicAdd(&pooled[cur * 64 + c], acc);
        if (c == 0) atomicAdd(&gcount[cur], cnt);
    }
    s1[tid] = sum; s2[tid] = ssq;
    __syncthreads();
    if (tid < 64) {
        int bin = blockIdx.x & 7;
        atomicAdd(&statsout[bin * 128 + tid],
                  s1[tid] + s1[tid + 64] + s1[tid + 128] + s1[tid + 192]);
        atomicAdd(&statsout[bin * 128 + 64 + tid],
                  s2[tid] + s2[tid + 64] + s2[tid + 128] + s2[tid + 192]);
    }
}

// ------- head: BN affine from binned stats folded via counts, mlp, log_softmax -------

__global__ void k_head(const float* __restrict__ pooled, const int* __restrict__ gcount,
                       const float* __restrict__ stats, const float* __restrict__ gamma,
                       const float* __restrict__ beta, const float* __restrict__ w1,
                       const float* __restrict__ b1, const float* __restrict__ w2,
                       const float* __restrict__ b2, float* __restrict__ out) {
    __shared__ float p[64];
    __shared__ float hid[64];
    __shared__ float o[2];
    int g = blockIdx.x, c = threadIdx.x;
    float s = 0.0f, q = 0.0f;
#pragma unroll
    for (int b = 0; b < 8; ++b) {
        s += stats[b * 128 + c];
        q += stats[b * 128 + 64 + c];
    }
    const float invn = 1.0f / (float)N_NODES;
    float mu = s * invn;
    float var = q * invn - mu * mu;
    float rs = rsqrtf(var + BN_EPS);
    float sc = gamma[c] * rs;
    float sh = beta[c] - sc * mu;
    p[c] = sc * pooled[g * 64 + c] + (float)gcount[g] * sh;
    __syncthreads();
    float acc = b1[c];
#pragma unroll
    for (int k = 0; k < 64; ++k) acc += p[k] * w1[k * 64 + c];
    hid[c] = fmaxf(acc, 0.0f);
    __syncthreads();
    if (c < 2) {
        float a = b2[c];
#pragma unroll
        for (int k = 0; k < 64; ++k) a += hid[k] * w2[k * 2 + c];
        o[c] = a;
    }
    __syncthreads();
    if (c == 0) {
        float m = fmaxf(o[0], o[1]);
        float l = m + logf(expf(o[0] - m) + expf(o[1] - m));
        out[g * 2 + 0] = o[0] - l;
        out[g * 2 + 1] = o[1] - l;
    }
}

extern "C" void kernel_launch(void* const* d_in, const int* in_sizes, int n_in,
                              void* d_out, int out_size, void* d_ws, size_t ws_size,
                              hipStream_t stream) {
    const float* x        = (const float*)d_in[0];
    const int*   ei       = (const int*)d_in[1];
    const int*   batch    = (const int*)d_in[2];
    const float* edge_attr= (const float*)d_in[3];
    const float* W0       = (const float*)d_in[4];
    const float* b0       = (const float*)d_in[5];
    const float* Ws       = (const float*)d_in[6];
    const float* bs       = (const float*)d_in[7];
    const float* gammas   = (const float*)d_in[8];
    const float* betas    = (const float*)d_in[9];
    const float* lin1_w   = (const float*)d_in[10];
    const float* lin1_b   = (const float*)d_in[11];
    const float* lin2_w   = (const float*)d_in[12];
    const float* lin2_b   = (const float*)d_in[13];
    float* out = (float*)d_out;

    const int* src = ei;
    const int* dst = ei + N_EDGES;

    // workspace layout (float units). csr/ebuf: NBUCK*BCAP int2 = 3,211,264 floats.
    float*  ws0      = (float*)d_ws;
    float*  dinv     = ws0;                             // [0, 100004)
    int*    offsets  = (int*)(ws0 + 100004);            // [100004, 200008)
    int*    ends     = (int*)(ws0 + 200008);            // [200008, 300012)
    int2*   csr      = (int2*)(ws0 + 300012);           // [300012, 3511276)
    bf16_t* tB       = (bf16_t*)(ws0 + 3511276);        // [3511276, 6711276)  u' rows
    bf16_t* rA       = (bf16_t*)(ws0 + 6711276);        // [6711276, 9911276)  r rows
    float*  stats    = ws0 + 9911276;                   // 3*1024
    float*  pooled   = stats + 3 * 1024;                // 16384
    int*    gcount   = (int*)(pooled + NGRAPH * 64);    // 256
    int*    bucket_cursor = (int*)(gcount + NGRAPH);    // 196 (zero-init by memset)
    float*  xs       = (float*)(bucket_cursor + 196);   // N*8 = 800000
    // transient alias: ebuf spans tB and the start of rA (dead after k_bsort;
    // tB first written by layer-1 affmm, rA by gather0x — both after bsort)
    int2*  ebuf = (int2*)tB;

    const int nblk_g   = N_NODES * 64 / 256;   // 25000 (wave per node)
    const int nblk_mm  = NTILES;               // 3125
    const int nblk_xs  = (N_NODES * 8 + 255) / 256;  // 3125

    // one memset: stats + pooled + gcount + bucket_cursor (contiguous)
    hipMemsetAsync(stats, 0, (3 * 1024 + NGRAPH * 64 + NGRAPH + NBUCK) * sizeof(float),
                   stream);

    // ---- CSR build: bucket fill -> in-bucket sort ----
    k_bfill<<<NBLK_B, 256, 0, stream>>>(src, dst, (const float2*)edge_attr,
                                        bucket_cursor, ebuf);
    k_bsort<<<NBUCK, 512, 0, stream>>>(bucket_cursor, ebuf, offsets, ends, csr, dinv);

    // ---- layer 0: xs = dinv∘x, then fused aggregation + 8x64 matvec -> r0 ----
    k_xscale<<<nblk_xs, 256, 0, stream>>>(x, dinv, xs);
    k_gather0x<<<nblk_g, 256, 0, stream>>>(xs, offsets, ends, csr, dinv, W0, b0, rA);
    k_bnstats<<<1024, 256, 0, stream>>>(rA, stats);

    // ---- layer 1 ----
    k_affmm<<<nblk_mm, 256, 0, stream>>>(rA, dinv, stats, gammas, betas, Ws, tB);
    k_gather<<<nblk_g, 256, 0, stream>>>(tB, offsets, ends, csr, dinv, bs, rA);
    k_bnstats<<<1024, 256, 0, stream>>>(rA, stats + 1024);

    // ---- layer 2 ----
    k_affmm<<<nblk_mm, 256, 0, stream>>>(rA, dinv, stats + 1024, gammas + 64, betas + 64,
                                         Ws + 64 * 64, tB);
    k_gather<<<nblk_g, 256, 0, stream>>>(tB, offsets, ends, csr, dinv, bs + 64, rA);

    // ---- pool (+ fused layer-2 stats) + head ----
    k_pool<<<(N_NODES + POOL_ROWS - 1) / POOL_ROWS, 256, 0, stream>>>(
        batch, rA, pooled, gcount, stats + 2048);
    k_head<<<NGRAPH, 64, 0, stream>>>(pooled, gcount, stats + 2048,
                                      gammas + 2 * 64, betas + 2 * 64,
                                      lin1_w, lin1_b, lin2_w, lin2_b, out);
}